// Round 2
// baseline (506.153 us; speedup 1.0000x reference)
//
#include <hip/hip_runtime.h>
#include <hip/hip_bf16.h>
#include <cstdint>
#include <cstddef>

#define NN 50000
#define EE 800000
#define FIN 512
#define HIDC 16
#define NH 8
#define HCH 128
#define NLBL 40
#define NLBLP 48
#define ETOT (EE + NN)
#define NEG_SLOPE 0.2f
#define ELU_A 0.2f
#define BN_EPS 1e-5f

typedef __attribute__((ext_vector_type(8))) short bf16x8;
typedef __attribute__((ext_vector_type(4))) float f32x4;

__device__ inline short f2b(float f) {
    __hip_bfloat16 h = __float2bfloat16(f);   // RNE
    return *reinterpret_cast<short*>(&h);
}
__device__ inline float blo(unsigned int u) {
    union { unsigned int u; float f; } v; v.u = u << 16; return v.f;
}
__device__ inline float bhi(unsigned int u) {
    union { unsigned int u; float f; } v; v.u = u & 0xffff0000u; return v.f;
}

// ---------------- weight transpose + bf16 convert: Wt[n][k] = bf16(W[k][n]) ----------------
__global__ __launch_bounds__(256) void k_convW(const float* __restrict__ W,
                                               short* __restrict__ Wt,
                                               int K, int N, int Np)
{
    int idx = blockIdx.x * blockDim.x + threadIdx.x;
    if (idx >= Np * K) return;
    int n = idx / K, k = idx - n * K;
    float v = (n < N) ? W[(size_t)k * N + n] : 0.f;
    Wt[idx] = f2b(v);
}

// ---------------- MFMA GEMM, LDS-staged B + register-ring A prefetch ----------------
// NTILES=2 (32-col tiles): doubles the grid vs NTILES=4 so the CU residency limit
// (8 blocks: VGPR/wave-slot bound) is actually reached -- round-1 showed the grid
// (6.1 blocks/CU) was the occupancy cap, not LDS/VGPR.
template<int KDIM, int NTILES, bool A_BF16>
__global__ __launch_bounds__(256) void k_gemm_lds(const void* __restrict__ Ap,
                                                  const short* __restrict__ Wt,
                                                  short* __restrict__ C,
                                                  int M, int N)
{
    constexpr int NFULL = NTILES * 16;
    constexpr int KCH = 128;               // k-chunk
    constexpr int NK = KDIM / 32;          // total ksteps
    constexpr int NCH = KDIM / KCH;        // chunks
    constexpr int LROW = KCH + 8;          // shorts per LDS row
    __shared__ short Bs[NFULL * LROW];

    const int tid  = threadIdx.x;
    const int wave = tid >> 6;
    const int lane = tid & 63;
    const int quad = lane >> 4;
    const int col  = lane & 15;
    const int cb   = blockIdx.y * NFULL;   // column base
    const int row  = blockIdx.x * 64 + wave * 16 + col;
    const int arow = row < M ? row : M - 1;

    f32x4 acc[NTILES];
    #pragma unroll
    for (int t = 0; t < NTILES; ++t) acc[t] = (f32x4){0.f, 0.f, 0.f, 0.f};

    bf16x8 arB[4];
    float4 arF[4][2];
    const short* Ab = (const short*)Ap;
    const float* Af = (const float*)Ap;
    auto pf = [&](int ks) {
        if (ks >= NK) return;
        if (A_BF16) {
            arB[ks & 3] = *(const bf16x8*)(Ab + (size_t)arow * KDIM + ks * 32 + quad * 8);
        } else {
            const float4* p = (const float4*)(Af + (size_t)arow * KDIM + ks * 32 + quad * 8);
            arF[ks & 3][0] = p[0];
            arF[ks & 3][1] = p[1];
        }
    };
    pf(0); pf(1); pf(2); pf(3);

    for (int c = 0; c < NCH; ++c) {
        const int k0 = c * KCH;
        constexpr int TOT8 = NFULL * (KCH / 8);
        #pragma unroll
        for (int i = tid; i < TOT8; i += 256) {
            int n  = i >> 4;
            int kk = i & 15;
            bf16x8 v = *(const bf16x8*)(Wt + (size_t)(cb + n) * KDIM + k0 + kk * 8);
            *(bf16x8*)(Bs + n * LROW + kk * 8) = v;
        }
        __syncthreads();
        #pragma unroll
        for (int s = 0; s < KCH / 32; ++s) {
            const int ks = c * (KCH / 32) + s;
            bf16x8 afrag;
            if (A_BF16) {
                afrag = arB[ks & 3];
            } else {
                float4 v0 = arF[ks & 3][0], v1 = arF[ks & 3][1];
                afrag[0] = f2b(v0.x); afrag[1] = f2b(v0.y);
                afrag[2] = f2b(v0.z); afrag[3] = f2b(v0.w);
                afrag[4] = f2b(v1.x); afrag[5] = f2b(v1.y);
                afrag[6] = f2b(v1.z); afrag[7] = f2b(v1.w);
            }
            pf(ks + 4);
            #pragma unroll
            for (int t = 0; t < NTILES; ++t) {
                bf16x8 bfrag = *(const bf16x8*)(Bs + (t * 16 + col) * LROW + s * 32 + quad * 8);
                acc[t] = __builtin_amdgcn_mfma_f32_16x16x32_bf16(afrag, bfrag, acc[t], 0, 0, 0);
            }
        }
        if (c + 1 < NCH) __syncthreads();
    }

    const int mbase = blockIdx.x * 64 + wave * 16 + quad * 4;
    #pragma unroll
    for (int t = 0; t < NTILES; ++t) {
        int cc = cb + t * 16 + col;
        if (cc < N) {
            #pragma unroll
            for (int r = 0; r < 4; ++r) {
                int m = mbase + r;
                if (m < M) C[(size_t)m * N + cc] = f2b(acc[t][r]);
            }
        }
    }
}

// ---------------- per-(node,head) attention logits from bf16 h ----------------
__global__ __launch_bounds__(256) void k_alpha(const unsigned short* __restrict__ h,
                                               const float* __restrict__ a_s,
                                               const float* __restrict__ a_d,
                                               float* __restrict__ as_o,
                                               float* __restrict__ ad_o)
{
    int idx = blockIdx.x * blockDim.x + threadIdx.x;   // n*NH + hh
    if (idx >= NN * NH) return;
    int hh = idx & (NH - 1);
    const uint4* hp = (const uint4*)(h + (size_t)idx * HIDC);
    uint4 q0 = hp[0], q1 = hp[1];
    unsigned int u[8] = {q0.x, q0.y, q0.z, q0.w, q1.x, q1.y, q1.z, q1.w};
    const float* ap = a_s + hh * HIDC;
    const float* dp = a_d + hh * HIDC;
    float ss = 0.f, dd = 0.f;
    #pragma unroll
    for (int i = 0; i < 8; ++i) {
        float f0 = blo(u[i]), f1 = bhi(u[i]);
        ss += f0 * ap[2 * i] + f1 * ap[2 * i + 1];
        dd += f0 * dp[2 * i] + f1 * dp[2 * i + 1];
    }
    as_o[idx] = ss;
    ad_o[idx] = dd;
}

__global__ __launch_bounds__(256) void k_alpha2(const unsigned short* __restrict__ h2,
                                                const float* __restrict__ a_s,
                                                const float* __restrict__ a_d,
                                                float* __restrict__ as_o,
                                                float* __restrict__ ad_o)
{
    int n = blockIdx.x * blockDim.x + threadIdx.x;
    if (n >= NN) return;
    const uint4* hp = (const uint4*)(h2 + (size_t)n * NLBL);
    float ss = 0.f, dd = 0.f;
    #pragma unroll
    for (int qi = 0; qi < 5; ++qi) {
        uint4 q = hp[qi];
        unsigned int u[4] = {q.x, q.y, q.z, q.w};
        #pragma unroll
        for (int j = 0; j < 4; ++j) {
            int c = qi * 8 + j * 2;
            float f0 = blo(u[j]), f1 = bhi(u[j]);
            ss += f0 * a_s[c] + f1 * a_s[c + 1];
            dd += f0 * a_d[c] + f1 * a_d[c + 1];
        }
    }
    as_o[n] = ss;
    ad_o[n] = dd;
}

// ---------------- CSR build ----------------
__global__ __launch_bounds__(256) void k_hist(const int* __restrict__ ei,
                                              int* __restrict__ deg)
{
    int e = blockIdx.x * blockDim.x + threadIdx.x;
    if (e >= ETOT) return;
    int dst = (e < EE) ? ei[EE + e] : (e - EE);
    atomicAdd(&deg[dst], 1);
}

__global__ __launch_bounds__(1024) void k_scan(const int* __restrict__ deg,
                                               int* __restrict__ row_ptr,
                                               int* __restrict__ cursor)
{
    __shared__ int sm[1024];
    __shared__ int carry;
    int tid = threadIdx.x;
    if (tid == 0) carry = 0;
    __syncthreads();
    for (int base = 0; base < NN; base += 8192) {
        int v[8];
        int s = 0;
        int i0 = base + tid * 8;
        #pragma unroll
        for (int j = 0; j < 8; ++j) {
            int i = i0 + j;
            v[j] = (i < NN) ? deg[i] : 0;
            s += v[j];
        }
        sm[tid] = s;
        __syncthreads();
        for (int ofs = 1; ofs < 1024; ofs <<= 1) {
            int t = (tid >= ofs) ? sm[tid - ofs] : 0;
            __syncthreads();
            sm[tid] += t;
            __syncthreads();
        }
        int excl = sm[tid] - s + carry;
        #pragma unroll
        for (int j = 0; j < 8; ++j) {
            int i = i0 + j;
            if (i < NN) { row_ptr[i] = excl; cursor[i] = excl; }
            excl += v[j];
        }
        int total = sm[1023];
        __syncthreads();
        if (tid == 0) carry += total;
        __syncthreads();
    }
    if (tid == 0) row_ptr[NN] = carry;   // == ETOT
}

__global__ __launch_bounds__(256) void k_scatter(const int* __restrict__ ei,
                                                 int* __restrict__ cursor,
                                                 int* __restrict__ csr_src)
{
    int e = blockIdx.x * blockDim.x + threadIdx.x;
    if (e >= ETOT) return;
    int src, dst;
    if (e < EE) { src = ei[e]; dst = ei[EE + e]; }
    else        { src = dst = e - EE; }
    int pos = atomicAdd(&cursor[dst], 1);
    csr_src[pos] = src;
}

// ---------------- pull aggregation: half-wave per edge stream, 4-deep unroll ----------------
__global__ __launch_bounds__(256) void k_agg(const int* __restrict__ row_ptr,
                                             const int* __restrict__ csr_src,
                                             const unsigned short* __restrict__ h,
                                             const float* __restrict__ as,
                                             const float* __restrict__ ad,
                                             const float* __restrict__ b,
                                             const float* __restrict__ g,
                                             const float* __restrict__ be,
                                             const float* __restrict__ rm,
                                             const float* __restrict__ rv,
                                             short* __restrict__ out)
{
    int n = blockIdx.x * 4 + (threadIdx.x >> 6);
    if (n >= NN) return;
    int lane = threadIdx.x & 63;
    int half = lane >> 5;
    int c4 = lane & 31;                  // channel group: channels 4*c4 .. 4*c4+3
    int hh = c4 >> 2;                    // head
    float adv = ad[n * NH + hh];
    float a0 = 0.f, a1 = 0.f, a2 = 0.f, a3 = 0.f, sw = 0.f;
    int jb = row_ptr[n], je = row_ptr[n + 1];
    int j = jb + half;
    for (; j + 6 < je; j += 8) {
        int s0 = csr_src[j];
        int s1 = csr_src[j + 2];
        int s2 = csr_src[j + 4];
        int s3 = csr_src[j + 6];
        float l0 = as[s0 * NH + hh] + adv;
        float l1 = as[s1 * NH + hh] + adv;
        float l2 = as[s2 * NH + hh] + adv;
        float l3 = as[s3 * NH + hh] + adv;
        uint2 u0 = *(const uint2*)(h + (size_t)s0 * HCH + 4 * c4);
        uint2 u1 = *(const uint2*)(h + (size_t)s1 * HCH + 4 * c4);
        uint2 u2 = *(const uint2*)(h + (size_t)s2 * HCH + 4 * c4);
        uint2 u3 = *(const uint2*)(h + (size_t)s3 * HCH + 4 * c4);
        l0 = l0 > 0.f ? l0 : NEG_SLOPE * l0;
        l1 = l1 > 0.f ? l1 : NEG_SLOPE * l1;
        l2 = l2 > 0.f ? l2 : NEG_SLOPE * l2;
        l3 = l3 > 0.f ? l3 : NEG_SLOPE * l3;
        float w0 = __expf(l0), w1 = __expf(l1), w2 = __expf(l2), w3 = __expf(l3);
        sw += (w0 + w1) + (w2 + w3);
        a0 += w0 * blo(u0.x) + w1 * blo(u1.x) + w2 * blo(u2.x) + w3 * blo(u3.x);
        a1 += w0 * bhi(u0.x) + w1 * bhi(u1.x) + w2 * bhi(u2.x) + w3 * bhi(u3.x);
        a2 += w0 * blo(u0.y) + w1 * blo(u1.y) + w2 * blo(u2.y) + w3 * blo(u3.y);
        a3 += w0 * bhi(u0.y) + w1 * bhi(u1.y) + w2 * bhi(u2.y) + w3 * bhi(u3.y);
    }
    for (; j < je; j += 2) {
        int s0 = csr_src[j];
        float l0 = as[s0 * NH + hh] + adv;
        uint2 u0 = *(const uint2*)(h + (size_t)s0 * HCH + 4 * c4);
        l0 = l0 > 0.f ? l0 : NEG_SLOPE * l0;
        float w0 = __expf(l0);
        sw += w0;
        a0 += w0 * blo(u0.x);
        a1 += w0 * bhi(u0.x);
        a2 += w0 * blo(u0.y);
        a3 += w0 * bhi(u0.y);
    }
    // combine the two half-waves
    a0 += __shfl_down(a0, 32);
    a1 += __shfl_down(a1, 32);
    a2 += __shfl_down(a2, 32);
    a3 += __shfl_down(a3, 32);
    sw += __shfl_down(sw, 32);
    if (half == 0) {
        int c = 4 * c4;
        float inv = 1.f / (sw + 1e-16f);
        float4 bv  = *(const float4*)(b + c);
        float4 gv  = *(const float4*)(g + c);
        float4 bev = *(const float4*)(be + c);
        float4 rmv = *(const float4*)(rm + c);
        float4 rvv = *(const float4*)(rv + c);
        float r0 = a0 * inv + bv.x;
        float r1 = a1 * inv + bv.y;
        float r2 = a2 * inv + bv.z;
        float r3 = a3 * inv + bv.w;
        r0 = (r0 - rmv.x) * (gv.x * rsqrtf(rvv.x + BN_EPS)) + bev.x;
        r1 = (r1 - rmv.y) * (gv.y * rsqrtf(rvv.y + BN_EPS)) + bev.y;
        r2 = (r2 - rmv.z) * (gv.z * rsqrtf(rvv.z + BN_EPS)) + bev.z;
        r3 = (r3 - rmv.w) * (gv.w * rsqrtf(rvv.w + BN_EPS)) + bev.w;
        r0 = r0 > 0.f ? r0 : ELU_A * expm1f(r0);
        r1 = r1 > 0.f ? r1 : ELU_A * expm1f(r1);
        r2 = r2 > 0.f ? r2 : ELU_A * expm1f(r2);
        r3 = r3 > 0.f ? r3 : ELU_A * expm1f(r3);
        unsigned int lo = (unsigned int)(unsigned short)f2b(r0) |
                          ((unsigned int)(unsigned short)f2b(r1) << 16);
        unsigned int hi = (unsigned int)(unsigned short)f2b(r2) |
                          ((unsigned int)(unsigned short)f2b(r3) << 16);
        *(uint2*)(out + (size_t)n * HCH + c) = make_uint2(lo, hi);
    }
}

// layer-2: 1 head, 40 ch bf16 gather, half-wave per edge stream, 4-deep unroll, fp32 out
__global__ __launch_bounds__(256) void k_agg2(const int* __restrict__ row_ptr,
                                              const int* __restrict__ csr_src,
                                              const unsigned short* __restrict__ h2,
                                              const float* __restrict__ as,
                                              const float* __restrict__ ad,
                                              const float* __restrict__ b,
                                              float* __restrict__ out)
{
    int n = blockIdx.x * 4 + (threadIdx.x >> 6);
    if (n >= NN) return;
    int lane = threadIdx.x & 63;
    int half = lane >> 5;                // which edge stream
    int c2 = lane & 31;                  // channel-pair index; active if c2 < 20
    bool act = c2 < 20;
    int coff = act ? 2 * c2 : 0;
    float adv = ad[n];
    float acc0 = 0.f, acc1 = 0.f, sw = 0.f;
    int jb = row_ptr[n], je = row_ptr[n + 1];
    int j = jb + half;
    for (; j + 6 < je; j += 8) {
        int s0 = csr_src[j];
        int s1 = csr_src[j + 2];
        int s2 = csr_src[j + 4];
        int s3 = csr_src[j + 6];
        float l0 = as[s0] + adv;
        float l1 = as[s1] + adv;
        float l2 = as[s2] + adv;
        float l3 = as[s3] + adv;
        unsigned int u0 = *(const unsigned int*)(h2 + (size_t)s0 * NLBL + coff);
        unsigned int u1 = *(const unsigned int*)(h2 + (size_t)s1 * NLBL + coff);
        unsigned int u2 = *(const unsigned int*)(h2 + (size_t)s2 * NLBL + coff);
        unsigned int u3 = *(const unsigned int*)(h2 + (size_t)s3 * NLBL + coff);
        l0 = l0 > 0.f ? l0 : NEG_SLOPE * l0;
        l1 = l1 > 0.f ? l1 : NEG_SLOPE * l1;
        l2 = l2 > 0.f ? l2 : NEG_SLOPE * l2;
        l3 = l3 > 0.f ? l3 : NEG_SLOPE * l3;
        float w0 = __expf(l0), w1 = __expf(l1), w2 = __expf(l2), w3 = __expf(l3);
        sw += (w0 + w1) + (w2 + w3);
        if (act) {
            acc0 += w0 * blo(u0) + w1 * blo(u1) + w2 * blo(u2) + w3 * blo(u3);
            acc1 += w0 * bhi(u0) + w1 * bhi(u1) + w2 * bhi(u2) + w3 * bhi(u3);
        }
    }
    for (; j < je; j += 2) {
        int s = csr_src[j];
        float l = as[s] + adv;
        unsigned int u = *(const unsigned int*)(h2 + (size_t)s * NLBL + coff);
        l = l > 0.f ? l : NEG_SLOPE * l;
        float w = __expf(l);
        sw += w;
        if (act) {
            acc0 += w * blo(u);
            acc1 += w * bhi(u);
        }
    }
    float acc0b = __shfl_down(acc0, 32);
    float acc1b = __shfl_down(acc1, 32);
    float swb   = __shfl_down(sw, 32);
    if (half == 0 && act) {
        acc0 += acc0b; acc1 += acc1b; sw += swb;
        float inv = 1.f / (sw + 1e-16f);
        out[(size_t)n * NLBL + 2 * c2]     = acc0 * inv + b[2 * c2];
        out[(size_t)n * NLBL + 2 * c2 + 1] = acc1 * inv + b[2 * c2 + 1];
    }
}

extern "C" void kernel_launch(void* const* d_in, const int* in_sizes, int n_in,
                              void* d_out, int out_size, void* d_ws, size_t ws_size,
                              hipStream_t stream)
{
    const float* x   = (const float*)d_in[0];
    const int*   ei  = (const int*)d_in[1];
    const float* W0  = (const float*)d_in[2];
    const float* as0 = (const float*)d_in[3];
    const float* ad0 = (const float*)d_in[4];
    const float* b0  = (const float*)d_in[5];
    const float* g0  = (const float*)d_in[6];
    const float* be0 = (const float*)d_in[7];
    const float* rm0 = (const float*)d_in[8];
    const float* rv0 = (const float*)d_in[9];
    const float* W1  = (const float*)d_in[10];
    const float* as1 = (const float*)d_in[11];
    const float* ad1 = (const float*)d_in[12];
    const float* b1  = (const float*)d_in[13];
    const float* g1  = (const float*)d_in[14];
    const float* be1 = (const float*)d_in[15];
    const float* rm1 = (const float*)d_in[16];
    const float* rv1 = (const float*)d_in[17];
    const float* W2  = (const float*)d_in[18];
    const float* a_s2 = (const float*)d_in[19];
    const float* a_d2 = (const float*)d_in[20];
    const float* b2  = (const float*)d_in[21];
    float* out = (float*)d_out;

    char* ws = (char*)d_ws;
    size_t off = 0;
    auto alloc = [&](size_t bytes) {
        void* p = (void*)(ws + off);
        off += (bytes + 255) & ~(size_t)255;
        return p;
    };
    short* hbuf   = (short*)alloc((size_t)NN * HCH * 2);   // bf16 GEMM out / gather source
    short* fbuf   = (short*)alloc((size_t)NN * HCH * 2);   // bf16 aggregated features (GEMM A input)
    float* asb    = (float*)alloc((size_t)NN * NH * 4);
    float* adb    = (float*)alloc((size_t)NN * NH * 4);
    int*   deg    = (int*)alloc((size_t)NN * 4);
    int*   rowp   = (int*)alloc((size_t)(NN + 1) * 4);
    int*   cursor = (int*)alloc((size_t)NN * 4);
    int*   csrs   = (int*)alloc((size_t)ETOT * 4);
    short* Wt0    = (short*)alloc((size_t)HCH * FIN * 2);
    short* Wt1    = (short*)alloc((size_t)HCH * HCH * 2);
    short* Wt2    = (short*)alloc((size_t)NLBLP * HCH * 2);
    short* h2     = hbuf;   // reuse: hbuf dead by layer 2

    const int T = 256;
    const int gE  = (ETOT + T - 1) / T;
    const int gNH = (NN * NH + T - 1) / T;
    const int gN4 = (NN + 3) / 4;
    const int gM  = (NN + 63) / 64;

    // ---------- weight prep ----------
    k_convW<<<(HCH * FIN + T - 1) / T, T, 0, stream>>>(W0, Wt0, FIN, HCH, HCH);
    k_convW<<<(HCH * HCH + T - 1) / T, T, 0, stream>>>(W1, Wt1, HCH, HCH, HCH);
    k_convW<<<(NLBLP * HCH + T - 1) / T, T, 0, stream>>>(W2, Wt2, HCH, NLBL, NLBLP);

    // ---------- CSR build (reused by all 3 layers) ----------
    hipMemsetAsync(deg, 0, (size_t)NN * 4, stream);
    k_hist<<<gE, T, 0, stream>>>(ei, deg);
    k_scan<<<1, 1024, 0, stream>>>(deg, rowp, cursor);
    k_scatter<<<gE, T, 0, stream>>>(ei, cursor, csrs);

    // ---------- layer 0 ----------
    k_gemm_lds<FIN, 2, false><<<dim3(gM, 4), T, 0, stream>>>(x, Wt0, hbuf, NN, HCH);
    k_alpha<<<gNH, T, 0, stream>>>((const unsigned short*)hbuf, as0, ad0, asb, adb);
    k_agg<<<gN4, T, 0, stream>>>(rowp, csrs, (const unsigned short*)hbuf, asb, adb,
                                 b0, g0, be0, rm0, rv0, fbuf);

    // ---------- layer 1 ----------
    k_gemm_lds<HCH, 2, true><<<dim3(gM, 4), T, 0, stream>>>(fbuf, Wt1, hbuf, NN, HCH);
    k_alpha<<<gNH, T, 0, stream>>>((const unsigned short*)hbuf, as1, ad1, asb, adb);
    k_agg<<<gN4, T, 0, stream>>>(rowp, csrs, (const unsigned short*)hbuf, asb, adb,
                                 b1, g1, be1, rm1, rv1, fbuf);

    // ---------- layer 2 ----------
    k_gemm_lds<HCH, 1, true><<<dim3(gM, 3), T, 0, stream>>>(fbuf, Wt2, h2, NN, NLBL);
    k_alpha2<<<(NN + T - 1) / T, T, 0, stream>>>((const unsigned short*)h2, a_s2, a_d2, asb, adb);
    k_agg2<<<gN4, T, 0, stream>>>(rowp, csrs, (const unsigned short*)h2, asb, adb, b2, out);
}

// Round 3
// 465.071 us; speedup vs baseline: 1.0883x; 1.0883x over previous
//
#include <hip/hip_runtime.h>
#include <hip/hip_bf16.h>
#include <cstdint>
#include <cstddef>

#define NN 50000
#define EE 800000
#define FIN 512
#define HIDC 16
#define NH 8
#define HCH 128
#define NLBL 40
#define NLBLP 48
#define ETOT (EE + NN)
#define NEG_SLOPE 0.2f
#define ELU_A 0.2f
#define BN_EPS 1e-5f

typedef __attribute__((ext_vector_type(8))) short bf16x8;
typedef __attribute__((ext_vector_type(4))) short bf16x4;
typedef __attribute__((ext_vector_type(4))) float f32x4;

__device__ inline short f2b(float f) {
    __hip_bfloat16 h = __float2bfloat16(f);   // RNE
    return *reinterpret_cast<short*>(&h);
}
__device__ inline float blo(unsigned int u) {
    union { unsigned int u; float f; } v; v.u = u << 16; return v.f;
}
__device__ inline float bhi(unsigned int u) {
    union { unsigned int u; float f; } v; v.u = u & 0xffff0000u; return v.f;
}

// ---------------- weight transpose + bf16 convert: Wt[n][k] = bf16(W[k][n]) ----------------
__global__ __launch_bounds__(256) void k_convW(const float* __restrict__ W,
                                               short* __restrict__ Wt,
                                               int K, int N, int Np)
{
    int idx = blockIdx.x * blockDim.x + threadIdx.x;
    if (idx >= Np * K) return;
    int n = idx / K, k = idx - n * K;
    float v = (n < N) ? W[(size_t)k * N + n] : 0.f;
    Wt[idx] = f2b(v);
}

// ---------------- MFMA GEMM v2: BOTH operands LDS-staged, full-N block (no column split) ----
// 512 threads = 8 waves (4 M-groups x 2 N-groups), block = 64 rows x 128 cols, grid.y = 1.
// Each A row is fetched exactly once chip-wide; staging loads are 32-lane-contiguous;
// fp32->bf16 conversion happens once in the staging pass; the inner loop has ZERO global
// dependence (5 ds_read_b128 + 4 MFMA per k-step). Next chunk's global loads issue right
// after the barrier so they overlap the MFMA phase.
template<int KDIM, bool A_BF16>
__global__ __launch_bounds__(512, 4) void k_gemm2(const void* __restrict__ Ap,
                                                  const short* __restrict__ Wt,
                                                  short* __restrict__ C,
                                                  int M)
{
    constexpr int KCH  = 128;              // k-chunk
    constexpr int NCH  = KDIM / KCH;       // chunks (layer0: 4, layer1: 1)
    constexpr int LROW = KCH + 8;          // shorts per LDS row (+pad: banks)
    __shared__ short As[64 * LROW];        // 17.4 KB
    __shared__ short Bs[128 * LROW];       // 34.8 KB  -> 52.2 KB total, 3 blocks/CU

    const int tid  = threadIdx.x;
    const int wv   = tid >> 6;
    const int lane = tid & 63;
    const int quad = lane >> 4;
    const int col  = lane & 15;
    const int wr   = wv >> 1;              // M-group 0..3  (16 rows each)
    const int wn   = wv & 1;               // N-group 0..1  (64 cols each)
    const int rowbase = blockIdx.x * 64;

    const float* Af = (const float*)Ap;
    const short* Ab = (const short*)Ap;

    float4 pa[4];                          // fp32 A staging regs (layer 0)
    bf16x8 pab[2];                         // bf16 A staging regs (layer 1)
    bf16x8 pb[4];                          // B staging regs

    auto loadA = [&](int c) {
        if constexpr (A_BF16) {
            #pragma unroll
            for (int r = 0; r < 2; ++r) {
                int gr = rowbase + r * 32 + (tid >> 4);
                gr = gr < M ? gr : M - 1;
                pab[r] = *(const bf16x8*)(Ab + (size_t)gr * KDIM + c * KCH + (tid & 15) * 8);
            }
        } else {
            #pragma unroll
            for (int r = 0; r < 4; ++r) {
                int gr = rowbase + r * 16 + (tid >> 5);
                gr = gr < M ? gr : M - 1;
                pa[r] = *(const float4*)(Af + (size_t)gr * KDIM + c * KCH + (tid & 31) * 4);
            }
        }
    };
    auto loadB = [&](int c) {
        #pragma unroll
        for (int r = 0; r < 4; ++r) {
            int n = r * 32 + (tid >> 4);
            pb[r] = *(const bf16x8*)(Wt + (size_t)n * KDIM + c * KCH + (tid & 15) * 8);
        }
    };
    auto writeAB = [&]() {
        if constexpr (A_BF16) {
            #pragma unroll
            for (int r = 0; r < 2; ++r) {
                int row = r * 32 + (tid >> 4);
                *(bf16x8*)(As + row * LROW + (tid & 15) * 8) = pab[r];
            }
        } else {
            #pragma unroll
            for (int r = 0; r < 4; ++r) {
                int row = r * 16 + (tid >> 5);
                bf16x4 w;
                w[0] = f2b(pa[r].x); w[1] = f2b(pa[r].y);
                w[2] = f2b(pa[r].z); w[3] = f2b(pa[r].w);
                *(bf16x4*)(As + row * LROW + (tid & 31) * 4) = w;
            }
        }
        #pragma unroll
        for (int r = 0; r < 4; ++r) {
            int n = r * 32 + (tid >> 4);
            *(bf16x8*)(Bs + n * LROW + (tid & 15) * 8) = pb[r];
        }
    };

    f32x4 acc[4];
    #pragma unroll
    for (int t = 0; t < 4; ++t) acc[t] = (f32x4){0.f, 0.f, 0.f, 0.f};

    loadA(0); loadB(0);

    for (int c = 0; c < NCH; ++c) {
        writeAB();                         // vmcnt waits inserted here by compiler
        __syncthreads();
        if (c + 1 < NCH) { loadA(c + 1); loadB(c + 1); }   // fly under MFMA phase
        #pragma unroll
        for (int s = 0; s < KCH / 32; ++s) {
            bf16x8 af = *(const bf16x8*)(As + (wr * 16 + col) * LROW + s * 32 + quad * 8);
            #pragma unroll
            for (int t = 0; t < 4; ++t) {
                bf16x8 bf = *(const bf16x8*)(Bs + (wn * 64 + t * 16 + col) * LROW + s * 32 + quad * 8);
                acc[t] = __builtin_amdgcn_mfma_f32_16x16x32_bf16(af, bf, acc[t], 0, 0, 0);
            }
        }
        if (c + 1 < NCH) __syncthreads();
    }

    const int mb = rowbase + wr * 16 + quad * 4;
    #pragma unroll
    for (int t = 0; t < 4; ++t) {
        int cc = wn * 64 + t * 16 + col;
        #pragma unroll
        for (int r = 0; r < 4; ++r) {
            int m = mb + r;
            if (m < M) C[(size_t)m * HCH + cc] = f2b(acc[t][r]);
        }
    }
}

// ---------------- MFMA GEMM (round-0 structure), kept for layer 2 (N=48 tile) ----------------
template<int KDIM, int NTILES, bool A_BF16>
__global__ __launch_bounds__(256) void k_gemm_lds(const void* __restrict__ Ap,
                                                  const short* __restrict__ Wt,
                                                  short* __restrict__ C,
                                                  int M, int N)
{
    constexpr int NFULL = NTILES * 16;
    constexpr int KCH = 128;               // k-chunk
    constexpr int NK = KDIM / 32;          // total ksteps
    constexpr int NCH = KDIM / KCH;        // chunks
    constexpr int LROW = KCH + 8;          // shorts per LDS row
    __shared__ short Bs[NFULL * LROW];

    const int tid  = threadIdx.x;
    const int wave = tid >> 6;
    const int lane = tid & 63;
    const int quad = lane >> 4;
    const int col  = lane & 15;
    const int cb   = blockIdx.y * NFULL;   // column base
    const int row  = blockIdx.x * 64 + wave * 16 + col;
    const int arow = row < M ? row : M - 1;

    f32x4 acc[NTILES];
    #pragma unroll
    for (int t = 0; t < NTILES; ++t) acc[t] = (f32x4){0.f, 0.f, 0.f, 0.f};

    bf16x8 arB[4];
    float4 arF[4][2];
    const short* Ab = (const short*)Ap;
    const float* Af = (const float*)Ap;
    auto pf = [&](int ks) {
        if (ks >= NK) return;
        if (A_BF16) {
            arB[ks & 3] = *(const bf16x8*)(Ab + (size_t)arow * KDIM + ks * 32 + quad * 8);
        } else {
            const float4* p = (const float4*)(Af + (size_t)arow * KDIM + ks * 32 + quad * 8);
            arF[ks & 3][0] = p[0];
            arF[ks & 3][1] = p[1];
        }
    };
    pf(0); pf(1); pf(2); pf(3);

    for (int c = 0; c < NCH; ++c) {
        const int k0 = c * KCH;
        constexpr int TOT8 = NFULL * (KCH / 8);
        #pragma unroll
        for (int i = tid; i < TOT8; i += 256) {
            int n  = i >> 4;
            int kk = i & 15;
            bf16x8 v = *(const bf16x8*)(Wt + (size_t)(cb + n) * KDIM + k0 + kk * 8);
            *(bf16x8*)(Bs + n * LROW + kk * 8) = v;
        }
        __syncthreads();
        #pragma unroll
        for (int s = 0; s < KCH / 32; ++s) {
            const int ks = c * (KCH / 32) + s;
            bf16x8 afrag;
            if (A_BF16) {
                afrag = arB[ks & 3];
            } else {
                float4 v0 = arF[ks & 3][0], v1 = arF[ks & 3][1];
                afrag[0] = f2b(v0.x); afrag[1] = f2b(v0.y);
                afrag[2] = f2b(v0.z); afrag[3] = f2b(v0.w);
                afrag[4] = f2b(v1.x); afrag[5] = f2b(v1.y);
                afrag[6] = f2b(v1.z); afrag[7] = f2b(v1.w);
            }
            pf(ks + 4);
            #pragma unroll
            for (int t = 0; t < NTILES; ++t) {
                bf16x8 bfrag = *(const bf16x8*)(Bs + (t * 16 + col) * LROW + s * 32 + quad * 8);
                acc[t] = __builtin_amdgcn_mfma_f32_16x16x32_bf16(afrag, bfrag, acc[t], 0, 0, 0);
            }
        }
        if (c + 1 < NCH) __syncthreads();
    }

    const int mbase = blockIdx.x * 64 + wave * 16 + quad * 4;
    #pragma unroll
    for (int t = 0; t < NTILES; ++t) {
        int cc = cb + t * 16 + col;
        if (cc < N) {
            #pragma unroll
            for (int r = 0; r < 4; ++r) {
                int m = mbase + r;
                if (m < M) C[(size_t)m * N + cc] = f2b(acc[t][r]);
            }
        }
    }
}

// ---------------- per-(node,head) attention logits from bf16 h ----------------
__global__ __launch_bounds__(256) void k_alpha(const unsigned short* __restrict__ h,
                                               const float* __restrict__ a_s,
                                               const float* __restrict__ a_d,
                                               float* __restrict__ as_o,
                                               float* __restrict__ ad_o)
{
    int idx = blockIdx.x * blockDim.x + threadIdx.x;   // n*NH + hh
    if (idx >= NN * NH) return;
    int hh = idx & (NH - 1);
    const uint4* hp = (const uint4*)(h + (size_t)idx * HIDC);
    uint4 q0 = hp[0], q1 = hp[1];
    unsigned int u[8] = {q0.x, q0.y, q0.z, q0.w, q1.x, q1.y, q1.z, q1.w};
    const float* ap = a_s + hh * HIDC;
    const float* dp = a_d + hh * HIDC;
    float ss = 0.f, dd = 0.f;
    #pragma unroll
    for (int i = 0; i < 8; ++i) {
        float f0 = blo(u[i]), f1 = bhi(u[i]);
        ss += f0 * ap[2 * i] + f1 * ap[2 * i + 1];
        dd += f0 * dp[2 * i] + f1 * dp[2 * i + 1];
    }
    as_o[idx] = ss;
    ad_o[idx] = dd;
}

__global__ __launch_bounds__(256) void k_alpha2(const unsigned short* __restrict__ h2,
                                                const float* __restrict__ a_s,
                                                const float* __restrict__ a_d,
                                                float* __restrict__ as_o,
                                                float* __restrict__ ad_o)
{
    int n = blockIdx.x * blockDim.x + threadIdx.x;
    if (n >= NN) return;
    const uint4* hp = (const uint4*)(h2 + (size_t)n * NLBL);
    float ss = 0.f, dd = 0.f;
    #pragma unroll
    for (int qi = 0; qi < 5; ++qi) {
        uint4 q = hp[qi];
        unsigned int u[4] = {q.x, q.y, q.z, q.w};
        #pragma unroll
        for (int j = 0; j < 4; ++j) {
            int c = qi * 8 + j * 2;
            float f0 = blo(u[j]), f1 = bhi(u[j]);
            ss += f0 * a_s[c] + f1 * a_s[c + 1];
            dd += f0 * a_d[c] + f1 * a_d[c + 1];
        }
    }
    as_o[n] = ss;
    ad_o[n] = dd;
}

// ---------------- CSR build ----------------
__global__ __launch_bounds__(256) void k_hist(const int* __restrict__ ei,
                                              int* __restrict__ deg)
{
    int e = blockIdx.x * blockDim.x + threadIdx.x;
    if (e >= ETOT) return;
    int dst = (e < EE) ? ei[EE + e] : (e - EE);
    atomicAdd(&deg[dst], 1);
}

__global__ __launch_bounds__(1024) void k_scan(const int* __restrict__ deg,
                                               int* __restrict__ row_ptr,
                                               int* __restrict__ cursor)
{
    __shared__ int sm[1024];
    __shared__ int carry;
    int tid = threadIdx.x;
    if (tid == 0) carry = 0;
    __syncthreads();
    for (int base = 0; base < NN; base += 8192) {
        int v[8];
        int s = 0;
        int i0 = base + tid * 8;
        #pragma unroll
        for (int j = 0; j < 8; ++j) {
            int i = i0 + j;
            v[j] = (i < NN) ? deg[i] : 0;
            s += v[j];
        }
        sm[tid] = s;
        __syncthreads();
        for (int ofs = 1; ofs < 1024; ofs <<= 1) {
            int t = (tid >= ofs) ? sm[tid - ofs] : 0;
            __syncthreads();
            sm[tid] += t;
            __syncthreads();
        }
        int excl = sm[tid] - s + carry;
        #pragma unroll
        for (int j = 0; j < 8; ++j) {
            int i = i0 + j;
            if (i < NN) { row_ptr[i] = excl; cursor[i] = excl; }
            excl += v[j];
        }
        int total = sm[1023];
        __syncthreads();
        if (tid == 0) carry += total;
        __syncthreads();
    }
    if (tid == 0) row_ptr[NN] = carry;   // == ETOT
}

__global__ __launch_bounds__(256) void k_scatter(const int* __restrict__ ei,
                                                 int* __restrict__ cursor,
                                                 int* __restrict__ csr_src)
{
    int e = blockIdx.x * blockDim.x + threadIdx.x;
    if (e >= ETOT) return;
    int src, dst;
    if (e < EE) { src = ei[e]; dst = ei[EE + e]; }
    else        { src = dst = e - EE; }
    int pos = atomicAdd(&cursor[dst], 1);
    csr_src[pos] = src;
}

// ---------------- pull aggregation: half-wave per edge stream, 4-deep unroll ----------------
__global__ __launch_bounds__(256) void k_agg(const int* __restrict__ row_ptr,
                                             const int* __restrict__ csr_src,
                                             const unsigned short* __restrict__ h,
                                             const float* __restrict__ as,
                                             const float* __restrict__ ad,
                                             const float* __restrict__ b,
                                             const float* __restrict__ g,
                                             const float* __restrict__ be,
                                             const float* __restrict__ rm,
                                             const float* __restrict__ rv,
                                             short* __restrict__ out)
{
    int n = blockIdx.x * 4 + (threadIdx.x >> 6);
    if (n >= NN) return;
    int lane = threadIdx.x & 63;
    int half = lane >> 5;
    int c4 = lane & 31;                  // channel group: channels 4*c4 .. 4*c4+3
    int hh = c4 >> 2;                    // head
    float adv = ad[n * NH + hh];
    float a0 = 0.f, a1 = 0.f, a2 = 0.f, a3 = 0.f, sw = 0.f;
    int jb = row_ptr[n], je = row_ptr[n + 1];
    int j = jb + half;
    for (; j + 6 < je; j += 8) {
        int s0 = csr_src[j];
        int s1 = csr_src[j + 2];
        int s2 = csr_src[j + 4];
        int s3 = csr_src[j + 6];
        float l0 = as[s0 * NH + hh] + adv;
        float l1 = as[s1 * NH + hh] + adv;
        float l2 = as[s2 * NH + hh] + adv;
        float l3 = as[s3 * NH + hh] + adv;
        uint2 u0 = *(const uint2*)(h + (size_t)s0 * HCH + 4 * c4);
        uint2 u1 = *(const uint2*)(h + (size_t)s1 * HCH + 4 * c4);
        uint2 u2 = *(const uint2*)(h + (size_t)s2 * HCH + 4 * c4);
        uint2 u3 = *(const uint2*)(h + (size_t)s3 * HCH + 4 * c4);
        l0 = l0 > 0.f ? l0 : NEG_SLOPE * l0;
        l1 = l1 > 0.f ? l1 : NEG_SLOPE * l1;
        l2 = l2 > 0.f ? l2 : NEG_SLOPE * l2;
        l3 = l3 > 0.f ? l3 : NEG_SLOPE * l3;
        float w0 = __expf(l0), w1 = __expf(l1), w2 = __expf(l2), w3 = __expf(l3);
        sw += (w0 + w1) + (w2 + w3);
        a0 += w0 * blo(u0.x) + w1 * blo(u1.x) + w2 * blo(u2.x) + w3 * blo(u3.x);
        a1 += w0 * bhi(u0.x) + w1 * bhi(u1.x) + w2 * bhi(u2.x) + w3 * bhi(u3.x);
        a2 += w0 * blo(u0.y) + w1 * blo(u1.y) + w2 * blo(u2.y) + w3 * blo(u3.y);
        a3 += w0 * bhi(u0.y) + w1 * bhi(u1.y) + w2 * bhi(u2.y) + w3 * bhi(u3.y);
    }
    for (; j < je; j += 2) {
        int s0 = csr_src[j];
        float l0 = as[s0 * NH + hh] + adv;
        uint2 u0 = *(const uint2*)(h + (size_t)s0 * HCH + 4 * c4);
        l0 = l0 > 0.f ? l0 : NEG_SLOPE * l0;
        float w0 = __expf(l0);
        sw += w0;
        a0 += w0 * blo(u0.x);
        a1 += w0 * bhi(u0.x);
        a2 += w0 * blo(u0.y);
        a3 += w0 * bhi(u0.y);
    }
    // combine the two half-waves
    a0 += __shfl_down(a0, 32);
    a1 += __shfl_down(a1, 32);
    a2 += __shfl_down(a2, 32);
    a3 += __shfl_down(a3, 32);
    sw += __shfl_down(sw, 32);
    if (half == 0) {
        int c = 4 * c4;
        float inv = 1.f / (sw + 1e-16f);
        float4 bv  = *(const float4*)(b + c);
        float4 gv  = *(const float4*)(g + c);
        float4 bev = *(const float4*)(be + c);
        float4 rmv = *(const float4*)(rm + c);
        float4 rvv = *(const float4*)(rv + c);
        float r0 = a0 * inv + bv.x;
        float r1 = a1 * inv + bv.y;
        float r2 = a2 * inv + bv.z;
        float r3 = a3 * inv + bv.w;
        r0 = (r0 - rmv.x) * (gv.x * rsqrtf(rvv.x + BN_EPS)) + bev.x;
        r1 = (r1 - rmv.y) * (gv.y * rsqrtf(rvv.y + BN_EPS)) + bev.y;
        r2 = (r2 - rmv.z) * (gv.z * rsqrtf(rvv.z + BN_EPS)) + bev.z;
        r3 = (r3 - rmv.w) * (gv.w * rsqrtf(rvv.w + BN_EPS)) + bev.w;
        r0 = r0 > 0.f ? r0 : ELU_A * expm1f(r0);
        r1 = r1 > 0.f ? r1 : ELU_A * expm1f(r1);
        r2 = r2 > 0.f ? r2 : ELU_A * expm1f(r2);
        r3 = r3 > 0.f ? r3 : ELU_A * expm1f(r3);
        unsigned int lo = (unsigned int)(unsigned short)f2b(r0) |
                          ((unsigned int)(unsigned short)f2b(r1) << 16);
        unsigned int hi = (unsigned int)(unsigned short)f2b(r2) |
                          ((unsigned int)(unsigned short)f2b(r3) << 16);
        *(uint2*)(out + (size_t)n * HCH + c) = make_uint2(lo, hi);
    }
}

// layer-2: 1 head, 40 ch bf16 gather, half-wave per edge stream, 4-deep unroll, fp32 out
__global__ __launch_bounds__(256) void k_agg2(const int* __restrict__ row_ptr,
                                              const int* __restrict__ csr_src,
                                              const unsigned short* __restrict__ h2,
                                              const float* __restrict__ as,
                                              const float* __restrict__ ad,
                                              const float* __restrict__ b,
                                              float* __restrict__ out)
{
    int n = blockIdx.x * 4 + (threadIdx.x >> 6);
    if (n >= NN) return;
    int lane = threadIdx.x & 63;
    int half = lane >> 5;                // which edge stream
    int c2 = lane & 31;                  // channel-pair index; active if c2 < 20
    bool act = c2 < 20;
    int coff = act ? 2 * c2 : 0;
    float adv = ad[n];
    float acc0 = 0.f, acc1 = 0.f, sw = 0.f;
    int jb = row_ptr[n], je = row_ptr[n + 1];
    int j = jb + half;
    for (; j + 6 < je; j += 8) {
        int s0 = csr_src[j];
        int s1 = csr_src[j + 2];
        int s2 = csr_src[j + 4];
        int s3 = csr_src[j + 6];
        float l0 = as[s0] + adv;
        float l1 = as[s1] + adv;
        float l2 = as[s2] + adv;
        float l3 = as[s3] + adv;
        unsigned int u0 = *(const unsigned int*)(h2 + (size_t)s0 * NLBL + coff);
        unsigned int u1 = *(const unsigned int*)(h2 + (size_t)s1 * NLBL + coff);
        unsigned int u2 = *(const unsigned int*)(h2 + (size_t)s2 * NLBL + coff);
        unsigned int u3 = *(const unsigned int*)(h2 + (size_t)s3 * NLBL + coff);
        l0 = l0 > 0.f ? l0 : NEG_SLOPE * l0;
        l1 = l1 > 0.f ? l1 : NEG_SLOPE * l1;
        l2 = l2 > 0.f ? l2 : NEG_SLOPE * l2;
        l3 = l3 > 0.f ? l3 : NEG_SLOPE * l3;
        float w0 = __expf(l0), w1 = __expf(l1), w2 = __expf(l2), w3 = __expf(l3);
        sw += (w0 + w1) + (w2 + w3);
        if (act) {
            acc0 += w0 * blo(u0) + w1 * blo(u1) + w2 * blo(u2) + w3 * blo(u3);
            acc1 += w0 * bhi(u0) + w1 * bhi(u1) + w2 * bhi(u2) + w3 * bhi(u3);
        }
    }
    for (; j < je; j += 2) {
        int s = csr_src[j];
        float l = as[s] + adv;
        unsigned int u = *(const unsigned int*)(h2 + (size_t)s * NLBL + coff);
        l = l > 0.f ? l : NEG_SLOPE * l;
        float w = __expf(l);
        sw += w;
        if (act) {
            acc0 += w * blo(u);
            acc1 += w * bhi(u);
        }
    }
    float acc0b = __shfl_down(acc0, 32);
    float acc1b = __shfl_down(acc1, 32);
    float swb   = __shfl_down(sw, 32);
    if (half == 0 && act) {
        acc0 += acc0b; acc1 += acc1b; sw += swb;
        float inv = 1.f / (sw + 1e-16f);
        out[(size_t)n * NLBL + 2 * c2]     = acc0 * inv + b[2 * c2];
        out[(size_t)n * NLBL + 2 * c2 + 1] = acc1 * inv + b[2 * c2 + 1];
    }
}

extern "C" void kernel_launch(void* const* d_in, const int* in_sizes, int n_in,
                              void* d_out, int out_size, void* d_ws, size_t ws_size,
                              hipStream_t stream)
{
    const float* x   = (const float*)d_in[0];
    const int*   ei  = (const int*)d_in[1];
    const float* W0  = (const float*)d_in[2];
    const float* as0 = (const float*)d_in[3];
    const float* ad0 = (const float*)d_in[4];
    const float* b0  = (const float*)d_in[5];
    const float* g0  = (const float*)d_in[6];
    const float* be0 = (const float*)d_in[7];
    const float* rm0 = (const float*)d_in[8];
    const float* rv0 = (const float*)d_in[9];
    const float* W1  = (const float*)d_in[10];
    const float* as1 = (const float*)d_in[11];
    const float* ad1 = (const float*)d_in[12];
    const float* b1  = (const float*)d_in[13];
    const float* g1  = (const float*)d_in[14];
    const float* be1 = (const float*)d_in[15];
    const float* rm1 = (const float*)d_in[16];
    const float* rv1 = (const float*)d_in[17];
    const float* W2  = (const float*)d_in[18];
    const float* a_s2 = (const float*)d_in[19];
    const float* a_d2 = (const float*)d_in[20];
    const float* b2  = (const float*)d_in[21];
    float* out = (float*)d_out;

    char* ws = (char*)d_ws;
    size_t off = 0;
    auto alloc = [&](size_t bytes) {
        void* p = (void*)(ws + off);
        off += (bytes + 255) & ~(size_t)255;
        return p;
    };
    short* hbuf   = (short*)alloc((size_t)NN * HCH * 2);   // bf16 GEMM out / gather source
    short* fbuf   = (short*)alloc((size_t)NN * HCH * 2);   // bf16 aggregated features (GEMM A input)
    float* asb    = (float*)alloc((size_t)NN * NH * 4);
    float* adb    = (float*)alloc((size_t)NN * NH * 4);
    int*   deg    = (int*)alloc((size_t)NN * 4);
    int*   rowp   = (int*)alloc((size_t)(NN + 1) * 4);
    int*   cursor = (int*)alloc((size_t)NN * 4);
    int*   csrs   = (int*)alloc((size_t)ETOT * 4);
    short* Wt0    = (short*)alloc((size_t)HCH * FIN * 2);
    short* Wt1    = (short*)alloc((size_t)HCH * HCH * 2);
    short* Wt2    = (short*)alloc((size_t)NLBLP * HCH * 2);
    short* h2     = hbuf;   // reuse: hbuf dead by layer 2

    const int T = 256;
    const int gE  = (ETOT + T - 1) / T;
    const int gNH = (NN * NH + T - 1) / T;
    const int gN4 = (NN + 3) / 4;
    const int gM  = (NN + 63) / 64;

    // ---------- weight prep ----------
    k_convW<<<(HCH * FIN + T - 1) / T, T, 0, stream>>>(W0, Wt0, FIN, HCH, HCH);
    k_convW<<<(HCH * HCH + T - 1) / T, T, 0, stream>>>(W1, Wt1, HCH, HCH, HCH);
    k_convW<<<(NLBLP * HCH + T - 1) / T, T, 0, stream>>>(W2, Wt2, HCH, NLBL, NLBLP);

    // ---------- CSR build (reused by all 3 layers) ----------
    hipMemsetAsync(deg, 0, (size_t)NN * 4, stream);
    k_hist<<<gE, T, 0, stream>>>(ei, deg);
    k_scan<<<1, 1024, 0, stream>>>(deg, rowp, cursor);
    k_scatter<<<gE, T, 0, stream>>>(ei, cursor, csrs);

    // ---------- layer 0 ----------
    k_gemm2<FIN, false><<<gM, 512, 0, stream>>>(x, Wt0, hbuf, NN);
    k_alpha<<<gNH, T, 0, stream>>>((const unsigned short*)hbuf, as0, ad0, asb, adb);
    k_agg<<<gN4, T, 0, stream>>>(rowp, csrs, (const unsigned short*)hbuf, asb, adb,
                                 b0, g0, be0, rm0, rv0, fbuf);

    // ---------- layer 1 ----------
    k_gemm2<HCH, true><<<gM, 512, 0, stream>>>(fbuf, Wt1, hbuf, NN);
    k_alpha<<<gNH, T, 0, stream>>>((const unsigned short*)hbuf, as1, ad1, asb, adb);
    k_agg<<<gN4, T, 0, stream>>>(rowp, csrs, (const unsigned short*)hbuf, asb, adb,
                                 b1, g1, be1, rm1, rv1, fbuf);

    // ---------- layer 2 ----------
    k_gemm_lds<HCH, 3, true><<<dim3(gM, 1), T, 0, stream>>>(fbuf, Wt2, h2, NN, NLBL);
    k_alpha2<<<(NN + T - 1) / T, T, 0, stream>>>((const unsigned short*)h2, a_s2, a_d2, asb, adb);
    k_agg2<<<gN4, T, 0, stream>>>(rowp, csrs, (const unsigned short*)h2, asb, adb, b2, out);
}

// Round 4
// 458.381 us; speedup vs baseline: 1.1042x; 1.0146x over previous
//
#include <hip/hip_runtime.h>
#include <hip/hip_bf16.h>
#include <cstdint>
#include <cstddef>

#define NN 50000
#define EE 800000
#define FIN 512
#define HIDC 16
#define NH 8
#define HCH 128
#define NLBL 40
#define NLBLP 48
#define ETOT (EE + NN)
#define NEG_SLOPE 0.2f
#define ELU_A 0.2f
#define BN_EPS 1e-5f
#define SCH 8192
#define NCHK 7          // ceil(NN/SCH)

typedef __attribute__((ext_vector_type(8))) short bf16x8;
typedef __attribute__((ext_vector_type(4))) short bf16x4;
typedef __attribute__((ext_vector_type(4))) float f32x4;

__device__ inline short f2b(float f) {
    __hip_bfloat16 h = __float2bfloat16(f);   // RNE
    return *reinterpret_cast<short*>(&h);
}
__device__ inline float blo(unsigned int u) {
    union { unsigned int u; float f; } v; v.u = u << 16; return v.f;
}
__device__ inline float bhi(unsigned int u) {
    union { unsigned int u; float f; } v; v.u = u & 0xffff0000u; return v.f;
}

// ---------------- fused prep: 3x weight transpose/convert + degree histogram ----------------
// All four jobs are mutually independent and gate everything else -> one launch.
// Segments: [0,256) convW0, [256,320) convW1, [320,344) convW2, [344,3665) hist.
__global__ __launch_bounds__(256) void k_prep(const float* __restrict__ W0, short* __restrict__ Wt0,
                                              const float* __restrict__ W1, short* __restrict__ Wt1,
                                              const float* __restrict__ W2, short* __restrict__ Wt2,
                                              const int* __restrict__ ei, int* __restrict__ deg)
{
    int b = blockIdx.x;
    int tid = threadIdx.x;
    if (b < 256) {                         // Wt0[n][k] = bf16(W0[k][n]), 128x512
        int idx = b * 256 + tid;
        int n = idx >> 9, k = idx & 511;
        Wt0[idx] = f2b(W0[(size_t)k * HCH + n]);
        return;
    }
    b -= 256;
    if (b < 64) {                          // Wt1, 128x128
        int idx = b * 256 + tid;
        int n = idx >> 7, k = idx & 127;
        Wt1[idx] = f2b(W1[(size_t)k * HCH + n]);
        return;
    }
    b -= 64;
    if (b < 24) {                          // Wt2, 48(pad)x128, zero-fill cols >= 40
        int idx = b * 256 + tid;
        int n = idx >> 7, k = idx & 127;
        Wt2[idx] = f2b(n < NLBL ? W2[(size_t)k * NLBL + n] : 0.f);
        return;
    }
    b -= 24;
    {                                      // degree histogram
        int e = b * 256 + tid;
        if (e < ETOT) {
            int dst = (e < EE) ? ei[EE + e] : (e - EE);
            atomicAdd(&deg[dst], 1);
        }
    }
}

// ---------------- multi-block exclusive scan (replaces single-CU 140-barrier scan) ----------
__global__ __launch_bounds__(1024) void k_scan1(const int* __restrict__ deg,
                                                int* __restrict__ row_ptr,
                                                int* __restrict__ tot)
{
    __shared__ int sm[1024];
    int b = blockIdx.x, tid = threadIdx.x;
    int i0 = b * SCH + tid * 8;
    int v[8];
    int s = 0;
    #pragma unroll
    for (int j = 0; j < 8; ++j) {
        int i = i0 + j;
        v[j] = (i < NN) ? deg[i] : 0;
        s += v[j];
    }
    sm[tid] = s;
    __syncthreads();
    for (int ofs = 1; ofs < 1024; ofs <<= 1) {
        int t = (tid >= ofs) ? sm[tid - ofs] : 0;
        __syncthreads();
        sm[tid] += t;
        __syncthreads();
    }
    int excl = sm[tid] - s;
    #pragma unroll
    for (int j = 0; j < 8; ++j) {
        int i = i0 + j;
        if (i < NN) row_ptr[i] = excl;
        excl += v[j];
    }
    if (tid == 1023) tot[b] = sm[1023];
}

__global__ __launch_bounds__(64) void k_scan2(const int* __restrict__ tot,
                                              int* __restrict__ totp,
                                              int* __restrict__ row_ptr)
{
    if (threadIdx.x == 0) {
        int run = 0;
        for (int i = 0; i < NCHK; ++i) { totp[i] = run; run += tot[i]; }
        row_ptr[NN] = run;                 // == ETOT
    }
}

__global__ __launch_bounds__(256) void k_scan3(int* __restrict__ row_ptr,
                                               int* __restrict__ cursor,
                                               const int* __restrict__ totp)
{
    int i = blockIdx.x * 256 + threadIdx.x;
    if (i < NN) {
        int v = row_ptr[i] + totp[i / SCH];
        row_ptr[i] = v;
        cursor[i] = v;
    }
}

// ---------------- MFMA GEMM: both operands LDS-staged, fused alpha epilogue --------------
// 512 threads = 8 waves (4 M-groups x 2 N-groups), block = 64 rows x 128 cols.
// Head hh = wn*4+t owns exactly the 16 cols of accumulator tile t -> attention logits
// as/ad are a 16-lane shfl reduce of the fp32 accumulator (k_alpha eliminated; also more
// accurate: reference computes logits from un-rounded h).
// SCAT=true additionally runs the CSR scatter in blocks >= GM0 (independent work, hides
// its ~12us under the GEMM).
constexpr int GM0 = (NN + 63) / 64;        // 782
template<int KDIM, bool A_BF16, bool SCAT>
__global__ __launch_bounds__(512, 4) void k_gemm2(const void* __restrict__ Ap,
                                                  const short* __restrict__ Wt,
                                                  short* __restrict__ C,
                                                  int M,
                                                  const float* __restrict__ a_s,
                                                  const float* __restrict__ a_d,
                                                  float* __restrict__ as_o,
                                                  float* __restrict__ ad_o,
                                                  const int* __restrict__ ei,
                                                  int* __restrict__ cursor,
                                                  int* __restrict__ csr_src)
{
    if constexpr (SCAT) {
        if (blockIdx.x >= GM0) {
            int e = (blockIdx.x - GM0) * 512 + threadIdx.x;
            if (e < ETOT) {
                int src, dst;
                if (e < EE) { src = ei[e]; dst = ei[EE + e]; }
                else        { src = dst = e - EE; }
                int pos = atomicAdd(&cursor[dst], 1);
                csr_src[pos] = src;
            }
            return;
        }
    }

    constexpr int KCH  = 128;              // k-chunk
    constexpr int NCH  = KDIM / KCH;       // chunks (layer0: 4, layer1: 1)
    constexpr int LROW = KCH + 8;          // shorts per LDS row (+pad: banks)
    __shared__ short As[64 * LROW];        // 17.4 KB
    __shared__ short Bs[128 * LROW];       // 34.8 KB  -> 52.2 KB total, 3 blocks/CU

    const int tid  = threadIdx.x;
    const int wv   = tid >> 6;
    const int lane = tid & 63;
    const int quad = lane >> 4;
    const int col  = lane & 15;
    const int wr   = wv >> 1;              // M-group 0..3  (16 rows each)
    const int wn   = wv & 1;               // N-group 0..1  (64 cols each)
    const int rowbase = blockIdx.x * 64;

    const float* Af = (const float*)Ap;
    const short* Ab = (const short*)Ap;

    float4 pa[4];                          // fp32 A staging regs (layer 0)
    bf16x8 pab[2];                         // bf16 A staging regs (layer 1)
    bf16x8 pb[4];                          // B staging regs

    auto loadA = [&](int c) {
        if constexpr (A_BF16) {
            #pragma unroll
            for (int r = 0; r < 2; ++r) {
                int gr = rowbase + r * 32 + (tid >> 4);
                gr = gr < M ? gr : M - 1;
                pab[r] = *(const bf16x8*)(Ab + (size_t)gr * KDIM + c * KCH + (tid & 15) * 8);
            }
        } else {
            #pragma unroll
            for (int r = 0; r < 4; ++r) {
                int gr = rowbase + r * 16 + (tid >> 5);
                gr = gr < M ? gr : M - 1;
                pa[r] = *(const float4*)(Af + (size_t)gr * KDIM + c * KCH + (tid & 31) * 4);
            }
        }
    };
    auto loadB = [&](int c) {
        #pragma unroll
        for (int r = 0; r < 4; ++r) {
            int n = r * 32 + (tid >> 4);
            pb[r] = *(const bf16x8*)(Wt + (size_t)n * KDIM + c * KCH + (tid & 15) * 8);
        }
    };
    auto writeAB = [&]() {
        if constexpr (A_BF16) {
            #pragma unroll
            for (int r = 0; r < 2; ++r) {
                int row = r * 32 + (tid >> 4);
                *(bf16x8*)(As + row * LROW + (tid & 15) * 8) = pab[r];
            }
        } else {
            #pragma unroll
            for (int r = 0; r < 4; ++r) {
                int row = r * 16 + (tid >> 5);
                bf16x4 w;
                w[0] = f2b(pa[r].x); w[1] = f2b(pa[r].y);
                w[2] = f2b(pa[r].z); w[3] = f2b(pa[r].w);
                *(bf16x4*)(As + row * LROW + (tid & 31) * 4) = w;
            }
        }
        #pragma unroll
        for (int r = 0; r < 4; ++r) {
            int n = r * 32 + (tid >> 4);
            *(bf16x8*)(Bs + n * LROW + (tid & 15) * 8) = pb[r];
        }
    };

    f32x4 acc[4];
    #pragma unroll
    for (int t = 0; t < 4; ++t) acc[t] = (f32x4){0.f, 0.f, 0.f, 0.f};

    loadA(0); loadB(0);

    for (int c = 0; c < NCH; ++c) {
        writeAB();
        __syncthreads();
        if (c + 1 < NCH) { loadA(c + 1); loadB(c + 1); }   // fly under MFMA phase
        #pragma unroll
        for (int s = 0; s < KCH / 32; ++s) {
            bf16x8 af = *(const bf16x8*)(As + (wr * 16 + col) * LROW + s * 32 + quad * 8);
            #pragma unroll
            for (int t = 0; t < 4; ++t) {
                bf16x8 bf = *(const bf16x8*)(Bs + (wn * 64 + t * 16 + col) * LROW + s * 32 + quad * 8);
                acc[t] = __builtin_amdgcn_mfma_f32_16x16x32_bf16(af, bf, acc[t], 0, 0, 0);
            }
        }
        if (c + 1 < NCH) __syncthreads();
    }

    const int mb = rowbase + wr * 16 + quad * 4;

    // C write (bf16)
    #pragma unroll
    for (int t = 0; t < 4; ++t) {
        int cc = wn * 64 + t * 16 + col;
        #pragma unroll
        for (int r = 0; r < 4; ++r) {
            int m = mb + r;
            if (m < M) C[(size_t)m * HCH + cc] = f2b(acc[t][r]);
        }
    }

    // fused attention logits: head hh = wn*4+t; 16-lane reduce over col
    #pragma unroll
    for (int t = 0; t < 4; ++t) {
        int hh = wn * 4 + t;
        float ws = a_s[hh * HIDC + col];
        float wd = a_d[hh * HIDC + col];
        #pragma unroll
        for (int r = 0; r < 4; ++r) {
            float vs = acc[t][r] * ws;
            float vd = acc[t][r] * wd;
            vs += __shfl_xor(vs, 1);  vd += __shfl_xor(vd, 1);
            vs += __shfl_xor(vs, 2);  vd += __shfl_xor(vd, 2);
            vs += __shfl_xor(vs, 4);  vd += __shfl_xor(vd, 4);
            vs += __shfl_xor(vs, 8);  vd += __shfl_xor(vd, 8);
            int m = mb + r;
            if (col == 0 && m < M) {
                as_o[m * NH + hh] = vs;
                ad_o[m * NH + hh] = vd;
            }
        }
    }
}

// ---------------- layer-2 GEMM (N=48 padded tile) with fused alpha2 epilogue --------------
template<int KDIM, int NTILES, bool A_BF16>
__global__ __launch_bounds__(256) void k_gemm_lds(const void* __restrict__ Ap,
                                                  const short* __restrict__ Wt,
                                                  short* __restrict__ C,
                                                  int M, int N,
                                                  const float* __restrict__ a_s2,
                                                  const float* __restrict__ a_d2,
                                                  float* __restrict__ as_o,
                                                  float* __restrict__ ad_o)
{
    constexpr int NFULL = NTILES * 16;
    constexpr int KCH = 128;               // k-chunk
    constexpr int NK = KDIM / 32;          // total ksteps
    constexpr int NCH = KDIM / KCH;        // chunks
    constexpr int LROW = KCH + 8;          // shorts per LDS row
    __shared__ short Bs[NFULL * LROW];

    const int tid  = threadIdx.x;
    const int wave = tid >> 6;
    const int lane = tid & 63;
    const int quad = lane >> 4;
    const int col  = lane & 15;
    const int row  = blockIdx.x * 64 + wave * 16 + col;
    const int arow = row < M ? row : M - 1;

    f32x4 acc[NTILES];
    #pragma unroll
    for (int t = 0; t < NTILES; ++t) acc[t] = (f32x4){0.f, 0.f, 0.f, 0.f};

    bf16x8 arB[4];
    float4 arF[4][2];
    const short* Ab = (const short*)Ap;
    const float* Af = (const float*)Ap;
    auto pf = [&](int ks) {
        if (ks >= NK) return;
        if (A_BF16) {
            arB[ks & 3] = *(const bf16x8*)(Ab + (size_t)arow * KDIM + ks * 32 + quad * 8);
        } else {
            const float4* p = (const float4*)(Af + (size_t)arow * KDIM + ks * 32 + quad * 8);
            arF[ks & 3][0] = p[0];
            arF[ks & 3][1] = p[1];
        }
    };
    pf(0); pf(1); pf(2); pf(3);

    for (int c = 0; c < NCH; ++c) {
        const int k0 = c * KCH;
        constexpr int TOT8 = NFULL * (KCH / 8);
        #pragma unroll
        for (int i = tid; i < TOT8; i += 256) {
            int n  = i >> 4;
            int kk = i & 15;
            bf16x8 v = *(const bf16x8*)(Wt + (size_t)n * KDIM + k0 + kk * 8);
            *(bf16x8*)(Bs + n * LROW + kk * 8) = v;
        }
        __syncthreads();
        #pragma unroll
        for (int s = 0; s < KCH / 32; ++s) {
            const int ks = c * (KCH / 32) + s;
            bf16x8 afrag;
            if (A_BF16) {
                afrag = arB[ks & 3];
            } else {
                float4 v0 = arF[ks & 3][0], v1 = arF[ks & 3][1];
                afrag[0] = f2b(v0.x); afrag[1] = f2b(v0.y);
                afrag[2] = f2b(v0.z); afrag[3] = f2b(v0.w);
                afrag[4] = f2b(v1.x); afrag[5] = f2b(v1.y);
                afrag[6] = f2b(v1.z); afrag[7] = f2b(v1.w);
            }
            pf(ks + 4);
            #pragma unroll
            for (int t = 0; t < NTILES; ++t) {
                bf16x8 bfrag = *(const bf16x8*)(Bs + (t * 16 + col) * LROW + s * 32 + quad * 8);
                acc[t] = __builtin_amdgcn_mfma_f32_16x16x32_bf16(afrag, bfrag, acc[t], 0, 0, 0);
            }
        }
        if (c + 1 < NCH) __syncthreads();
    }

    const int mbase = blockIdx.x * 64 + wave * 16 + quad * 4;
    #pragma unroll
    for (int t = 0; t < NTILES; ++t) {
        int cc = t * 16 + col;
        if (cc < N) {
            #pragma unroll
            for (int r = 0; r < 4; ++r) {
                int m = mbase + r;
                if (m < M) C[(size_t)m * N + cc] = f2b(acc[t][r]);
            }
        }
    }

    // fused alpha2: single head spanning cols 0..39 (cols >= 40 have zero W -> acc==0)
    float vs[4] = {0.f, 0.f, 0.f, 0.f};
    float vd[4] = {0.f, 0.f, 0.f, 0.f};
    #pragma unroll
    for (int t = 0; t < NTILES; ++t) {
        int cc = t * 16 + col;
        float ws = cc < NLBL ? a_s2[cc] : 0.f;
        float wd = cc < NLBL ? a_d2[cc] : 0.f;
        #pragma unroll
        for (int r = 0; r < 4; ++r) {
            vs[r] += acc[t][r] * ws;
            vd[r] += acc[t][r] * wd;
        }
    }
    #pragma unroll
    for (int r = 0; r < 4; ++r) {
        float s = vs[r], d = vd[r];
        s += __shfl_xor(s, 1);  d += __shfl_xor(d, 1);
        s += __shfl_xor(s, 2);  d += __shfl_xor(d, 2);
        s += __shfl_xor(s, 4);  d += __shfl_xor(d, 4);
        s += __shfl_xor(s, 8);  d += __shfl_xor(d, 8);
        int m = mbase + r;
        if (col == 0 && m < M) {
            as_o[m] = s;
            ad_o[m] = d;
        }
    }
}

// ---------------- pull aggregation: half-wave per edge stream, 4-deep unroll ----------------
__global__ __launch_bounds__(256) void k_agg(const int* __restrict__ row_ptr,
                                             const int* __restrict__ csr_src,
                                             const unsigned short* __restrict__ h,
                                             const float* __restrict__ as,
                                             const float* __restrict__ ad,
                                             const float* __restrict__ b,
                                             const float* __restrict__ g,
                                             const float* __restrict__ be,
                                             const float* __restrict__ rm,
                                             const float* __restrict__ rv,
                                             short* __restrict__ out)
{
    int n = blockIdx.x * 4 + (threadIdx.x >> 6);
    if (n >= NN) return;
    int lane = threadIdx.x & 63;
    int half = lane >> 5;
    int c4 = lane & 31;                  // channel group: channels 4*c4 .. 4*c4+3
    int hh = c4 >> 2;                    // head
    float adv = ad[n * NH + hh];
    float a0 = 0.f, a1 = 0.f, a2 = 0.f, a3 = 0.f, sw = 0.f;
    int jb = row_ptr[n], je = row_ptr[n + 1];
    int j = jb + half;
    for (; j + 6 < je; j += 8) {
        int s0 = csr_src[j];
        int s1 = csr_src[j + 2];
        int s2 = csr_src[j + 4];
        int s3 = csr_src[j + 6];
        float l0 = as[s0 * NH + hh] + adv;
        float l1 = as[s1 * NH + hh] + adv;
        float l2 = as[s2 * NH + hh] + adv;
        float l3 = as[s3 * NH + hh] + adv;
        uint2 u0 = *(const uint2*)(h + (size_t)s0 * HCH + 4 * c4);
        uint2 u1 = *(const uint2*)(h + (size_t)s1 * HCH + 4 * c4);
        uint2 u2 = *(const uint2*)(h + (size_t)s2 * HCH + 4 * c4);
        uint2 u3 = *(const uint2*)(h + (size_t)s3 * HCH + 4 * c4);
        l0 = l0 > 0.f ? l0 : NEG_SLOPE * l0;
        l1 = l1 > 0.f ? l1 : NEG_SLOPE * l1;
        l2 = l2 > 0.f ? l2 : NEG_SLOPE * l2;
        l3 = l3 > 0.f ? l3 : NEG_SLOPE * l3;
        float w0 = __expf(l0), w1 = __expf(l1), w2 = __expf(l2), w3 = __expf(l3);
        sw += (w0 + w1) + (w2 + w3);
        a0 += w0 * blo(u0.x) + w1 * blo(u1.x) + w2 * blo(u2.x) + w3 * blo(u3.x);
        a1 += w0 * bhi(u0.x) + w1 * bhi(u1.x) + w2 * bhi(u2.x) + w3 * bhi(u3.x);
        a2 += w0 * blo(u0.y) + w1 * blo(u1.y) + w2 * blo(u2.y) + w3 * blo(u3.y);
        a3 += w0 * bhi(u0.y) + w1 * bhi(u1.y) + w2 * bhi(u2.y) + w3 * bhi(u3.y);
    }
    for (; j < je; j += 2) {
        int s0 = csr_src[j];
        float l0 = as[s0 * NH + hh] + adv;
        uint2 u0 = *(const uint2*)(h + (size_t)s0 * HCH + 4 * c4);
        l0 = l0 > 0.f ? l0 : NEG_SLOPE * l0;
        float w0 = __expf(l0);
        sw += w0;
        a0 += w0 * blo(u0.x);
        a1 += w0 * bhi(u0.x);
        a2 += w0 * blo(u0.y);
        a3 += w0 * bhi(u0.y);
    }
    // combine the two half-waves
    a0 += __shfl_down(a0, 32);
    a1 += __shfl_down(a1, 32);
    a2 += __shfl_down(a2, 32);
    a3 += __shfl_down(a3, 32);
    sw += __shfl_down(sw, 32);
    if (half == 0) {
        int c = 4 * c4;
        float inv = 1.f / (sw + 1e-16f);
        float4 bv  = *(const float4*)(b + c);
        float4 gv  = *(const float4*)(g + c);
        float4 bev = *(const float4*)(be + c);
        float4 rmv = *(const float4*)(rm + c);
        float4 rvv = *(const float4*)(rv + c);
        float r0 = a0 * inv + bv.x;
        float r1 = a1 * inv + bv.y;
        float r2 = a2 * inv + bv.z;
        float r3 = a3 * inv + bv.w;
        r0 = (r0 - rmv.x) * (gv.x * rsqrtf(rvv.x + BN_EPS)) + bev.x;
        r1 = (r1 - rmv.y) * (gv.y * rsqrtf(rvv.y + BN_EPS)) + bev.y;
        r2 = (r2 - rmv.z) * (gv.z * rsqrtf(rvv.z + BN_EPS)) + bev.z;
        r3 = (r3 - rmv.w) * (gv.w * rsqrtf(rvv.w + BN_EPS)) + bev.w;
        r0 = r0 > 0.f ? r0 : ELU_A * expm1f(r0);
        r1 = r1 > 0.f ? r1 : ELU_A * expm1f(r1);
        r2 = r2 > 0.f ? r2 : ELU_A * expm1f(r2);
        r3 = r3 > 0.f ? r3 : ELU_A * expm1f(r3);
        unsigned int lo = (unsigned int)(unsigned short)f2b(r0) |
                          ((unsigned int)(unsigned short)f2b(r1) << 16);
        unsigned int hi = (unsigned int)(unsigned short)f2b(r2) |
                          ((unsigned int)(unsigned short)f2b(r3) << 16);
        *(uint2*)(out + (size_t)n * HCH + c) = make_uint2(lo, hi);
    }
}

// layer-2: 1 head, 40 ch bf16 gather, half-wave per edge stream, 4-deep unroll, fp32 out
__global__ __launch_bounds__(256) void k_agg2(const int* __restrict__ row_ptr,
                                              const int* __restrict__ csr_src,
                                              const unsigned short* __restrict__ h2,
                                              const float* __restrict__ as,
                                              const float* __restrict__ ad,
                                              const float* __restrict__ b,
                                              float* __restrict__ out)
{
    int n = blockIdx.x * 4 + (threadIdx.x >> 6);
    if (n >= NN) return;
    int lane = threadIdx.x & 63;
    int half = lane >> 5;                // which edge stream
    int c2 = lane & 31;                  // channel-pair index; active if c2 < 20
    bool act = c2 < 20;
    int coff = act ? 2 * c2 : 0;
    float adv = ad[n];
    float acc0 = 0.f, acc1 = 0.f, sw = 0.f;
    int jb = row_ptr[n], je = row_ptr[n + 1];
    int j = jb + half;
    for (; j + 6 < je; j += 8) {
        int s0 = csr_src[j];
        int s1 = csr_src[j + 2];
        int s2 = csr_src[j + 4];
        int s3 = csr_src[j + 6];
        float l0 = as[s0] + adv;
        float l1 = as[s1] + adv;
        float l2 = as[s2] + adv;
        float l3 = as[s3] + adv;
        unsigned int u0 = *(const unsigned int*)(h2 + (size_t)s0 * NLBL + coff);
        unsigned int u1 = *(const unsigned int*)(h2 + (size_t)s1 * NLBL + coff);
        unsigned int u2 = *(const unsigned int*)(h2 + (size_t)s2 * NLBL + coff);
        unsigned int u3 = *(const unsigned int*)(h2 + (size_t)s3 * NLBL + coff);
        l0 = l0 > 0.f ? l0 : NEG_SLOPE * l0;
        l1 = l1 > 0.f ? l1 : NEG_SLOPE * l1;
        l2 = l2 > 0.f ? l2 : NEG_SLOPE * l2;
        l3 = l3 > 0.f ? l3 : NEG_SLOPE * l3;
        float w0 = __expf(l0), w1 = __expf(l1), w2 = __expf(l2), w3 = __expf(l3);
        sw += (w0 + w1) + (w2 + w3);
        if (act) {
            acc0 += w0 * blo(u0) + w1 * blo(u1) + w2 * blo(u2) + w3 * blo(u3);
            acc1 += w0 * bhi(u0) + w1 * bhi(u1) + w2 * bhi(u2) + w3 * bhi(u3);
        }
    }
    for (; j < je; j += 2) {
        int s = csr_src[j];
        float l = as[s] + adv;
        unsigned int u = *(const unsigned int*)(h2 + (size_t)s * NLBL + coff);
        l = l > 0.f ? l : NEG_SLOPE * l;
        float w = __expf(l);
        sw += w;
        if (act) {
            acc0 += w * blo(u);
            acc1 += w * bhi(u);
        }
    }
    float acc0b = __shfl_down(acc0, 32);
    float acc1b = __shfl_down(acc1, 32);
    float swb   = __shfl_down(sw, 32);
    if (half == 0 && act) {
        acc0 += acc0b; acc1 += acc1b; sw += swb;
        float inv = 1.f / (sw + 1e-16f);
        out[(size_t)n * NLBL + 2 * c2]     = acc0 * inv + b[2 * c2];
        out[(size_t)n * NLBL + 2 * c2 + 1] = acc1 * inv + b[2 * c2 + 1];
    }
}

extern "C" void kernel_launch(void* const* d_in, const int* in_sizes, int n_in,
                              void* d_out, int out_size, void* d_ws, size_t ws_size,
                              hipStream_t stream)
{
    const float* x   = (const float*)d_in[0];
    const int*   ei  = (const int*)d_in[1];
    const float* W0  = (const float*)d_in[2];
    const float* as0 = (const float*)d_in[3];
    const float* ad0 = (const float*)d_in[4];
    const float* b0  = (const float*)d_in[5];
    const float* g0  = (const float*)d_in[6];
    const float* be0 = (const float*)d_in[7];
    const float* rm0 = (const float*)d_in[8];
    const float* rv0 = (const float*)d_in[9];
    const float* W1  = (const float*)d_in[10];
    const float* as1 = (const float*)d_in[11];
    const float* ad1 = (const float*)d_in[12];
    const float* b1  = (const float*)d_in[13];
    const float* g1  = (const float*)d_in[14];
    const float* be1 = (const float*)d_in[15];
    const float* rm1 = (const float*)d_in[16];
    const float* rv1 = (const float*)d_in[17];
    const float* W2  = (const float*)d_in[18];
    const float* a_s2 = (const float*)d_in[19];
    const float* a_d2 = (const float*)d_in[20];
    const float* b2  = (const float*)d_in[21];
    float* out = (float*)d_out;

    char* ws = (char*)d_ws;
    size_t off = 0;
    auto alloc = [&](size_t bytes) {
        void* p = (void*)(ws + off);
        off += (bytes + 255) & ~(size_t)255;
        return p;
    };
    short* hbuf   = (short*)alloc((size_t)NN * HCH * 2);   // bf16 GEMM out / gather source
    short* fbuf   = (short*)alloc((size_t)NN * HCH * 2);   // bf16 aggregated features (GEMM A input)
    float* asb    = (float*)alloc((size_t)NN * NH * 4);
    float* adb    = (float*)alloc((size_t)NN * NH * 4);
    int*   deg    = (int*)alloc((size_t)NN * 4);
    int*   rowp   = (int*)alloc((size_t)(NN + 1) * 4);
    int*   cursor = (int*)alloc((size_t)NN * 4);
    int*   csrs   = (int*)alloc((size_t)ETOT * 4);
    short* Wt0    = (short*)alloc((size_t)HCH * FIN * 2);
    short* Wt1    = (short*)alloc((size_t)HCH * HCH * 2);
    short* Wt2    = (short*)alloc((size_t)NLBLP * HCH * 2);
    int*   tot    = (int*)alloc(64 * 4);
    int*   totp   = (int*)alloc(64 * 4);
    short* h2     = hbuf;   // reuse: hbuf dead by layer 2

    const int T = 256;
    const int gN4 = (NN + 3) / 4;
    const int gM  = (NN + 63) / 64;        // 782 == GM0
    const int gPrep = 256 + 64 + 24 + (ETOT + T - 1) / T;   // 3665
    const int gScat = (ETOT + 511) / 512;                   // 1661

    // ---------- prep: weight transpose/convert + degree histogram (one launch) ----------
    hipMemsetAsync(deg, 0, (size_t)NN * 4, stream);
    k_prep<<<gPrep, T, 0, stream>>>(W0, Wt0, W1, Wt1, W2, Wt2, ei, deg);

    // ---------- multi-block scan ----------
    k_scan1<<<NCHK, 1024, 0, stream>>>(deg, rowp, tot);
    k_scan2<<<1, 64, 0, stream>>>(tot, totp, rowp);
    k_scan3<<<(NN + T - 1) / T, T, 0, stream>>>(rowp, cursor, totp);

    // ---------- layer 0 (GEMM + fused alpha epilogue, CSR scatter hidden in same launch) --
    k_gemm2<FIN, false, true><<<gM + gScat, 512, 0, stream>>>(x, Wt0, hbuf, NN,
                                                              as0, ad0, asb, adb,
                                                              ei, cursor, csrs);
    k_agg<<<gN4, T, 0, stream>>>(rowp, csrs, (const unsigned short*)hbuf, asb, adb,
                                 b0, g0, be0, rm0, rv0, fbuf);

    // ---------- layer 1 ----------
    k_gemm2<HCH, true, false><<<gM, 512, 0, stream>>>(fbuf, Wt1, hbuf, NN,
                                                      as1, ad1, asb, adb,
                                                      nullptr, nullptr, nullptr);
    k_agg<<<gN4, T, 0, stream>>>(rowp, csrs, (const unsigned short*)hbuf, asb, adb,
                                 b1, g1, be1, rm1, rv1, fbuf);

    // ---------- layer 2 (GEMM + fused alpha2 epilogue) ----------
    k_gemm_lds<HCH, 3, true><<<gM, T, 0, stream>>>(fbuf, Wt2, h2, NN, NLBL,
                                                   a_s2, a_d2, asb, adb);
    k_agg2<<<gN4, T, 0, stream>>>(rowp, csrs, (const unsigned short*)h2, asb, adb, b2, out);
}

// Round 5
// 455.492 us; speedup vs baseline: 1.1112x; 1.0063x over previous
//
#include <hip/hip_runtime.h>
#include <hip/hip_bf16.h>
#include <cstdint>
#include <cstddef>

#define NN 50000
#define EE 800000
#define FIN 512
#define HIDC 16
#define NH 8
#define HCH 128
#define NLBL 40
#define NLBLP 48
#define ETOT (EE + NN)
#define NEG_SLOPE 0.2f
#define ELU_A 0.2f
#define BN_EPS 1e-5f
#define SCH 8192
#define NCHK 7          // ceil(NN/SCH)

typedef __attribute__((ext_vector_type(8))) short bf16x8;
typedef __attribute__((ext_vector_type(4))) short bf16x4;
typedef __attribute__((ext_vector_type(4))) float f32x4;

__device__ inline short f2b(float f) {
    __hip_bfloat16 h = __float2bfloat16(f);   // RNE
    return *reinterpret_cast<short*>(&h);
}
__device__ inline float blo(unsigned int u) {
    union { unsigned int u; float f; } v; v.u = u << 16; return v.f;
}
__device__ inline float bhi(unsigned int u) {
    union { unsigned int u; float f; } v; v.u = u & 0xffff0000u; return v.f;
}

// ---------------- fused prep: 3x weight transpose/convert + degree histogram ----------------
__global__ __launch_bounds__(256) void k_prep(const float* __restrict__ W0, short* __restrict__ Wt0,
                                              const float* __restrict__ W1, short* __restrict__ Wt1,
                                              const float* __restrict__ W2, short* __restrict__ Wt2,
                                              const int* __restrict__ ei, int* __restrict__ deg)
{
    int b = blockIdx.x;
    int tid = threadIdx.x;
    if (b < 256) {                         // Wt0[n][k] = bf16(W0[k][n]), 128x512
        int idx = b * 256 + tid;
        int n = idx >> 9, k = idx & 511;
        Wt0[idx] = f2b(W0[(size_t)k * HCH + n]);
        return;
    }
    b -= 256;
    if (b < 64) {                          // Wt1, 128x128
        int idx = b * 256 + tid;
        int n = idx >> 7, k = idx & 127;
        Wt1[idx] = f2b(W1[(size_t)k * HCH + n]);
        return;
    }
    b -= 64;
    if (b < 24) {                          // Wt2, 48(pad)x128, zero-fill cols >= 40
        int idx = b * 256 + tid;
        int n = idx >> 7, k = idx & 127;
        Wt2[idx] = f2b(n < NLBL ? W2[(size_t)k * NLBL + n] : 0.f);
        return;
    }
    b -= 24;
    {                                      // degree histogram
        int e = b * 256 + tid;
        if (e < ETOT) {
            int dst = (e < EE) ? ei[EE + e] : (e - EE);
            atomicAdd(&deg[dst], 1);
        }
    }
}

// ---------------- multi-block exclusive scan ----------------
__global__ __launch_bounds__(1024) void k_scan1(const int* __restrict__ deg,
                                                int* __restrict__ row_ptr,
                                                int* __restrict__ tot)
{
    __shared__ int sm[1024];
    int b = blockIdx.x, tid = threadIdx.x;
    int i0 = b * SCH + tid * 8;
    int v[8];
    int s = 0;
    #pragma unroll
    for (int j = 0; j < 8; ++j) {
        int i = i0 + j;
        v[j] = (i < NN) ? deg[i] : 0;
        s += v[j];
    }
    sm[tid] = s;
    __syncthreads();
    for (int ofs = 1; ofs < 1024; ofs <<= 1) {
        int t = (tid >= ofs) ? sm[tid - ofs] : 0;
        __syncthreads();
        sm[tid] += t;
        __syncthreads();
    }
    int excl = sm[tid] - s;
    #pragma unroll
    for (int j = 0; j < 8; ++j) {
        int i = i0 + j;
        if (i < NN) row_ptr[i] = excl;
        excl += v[j];
    }
    if (tid == 1023) tot[b] = sm[1023];
}

__global__ __launch_bounds__(64) void k_scan2(const int* __restrict__ tot,
                                              int* __restrict__ totp,
                                              int* __restrict__ row_ptr)
{
    if (threadIdx.x == 0) {
        int run = 0;
        for (int i = 0; i < NCHK; ++i) { totp[i] = run; run += tot[i]; }
        row_ptr[NN] = run;                 // == ETOT
    }
}

__global__ __launch_bounds__(256) void k_scan3(int* __restrict__ row_ptr,
                                               int* __restrict__ cursor,
                                               const int* __restrict__ totp)
{
    int i = blockIdx.x * 256 + threadIdx.x;
    if (i < NN) {
        int v = row_ptr[i] + totp[i / SCH];
        row_ptr[i] = v;
        cursor[i] = v;
    }
}

// ---------------- CSR scatter (separate launch: fusing it into the GEMM congested L2,
// round-4: fused dispatch 97us vs ~52us serialized; write-amplified atomics + streaming
// GEMM reads fight for the same fabric) ----------------
__global__ __launch_bounds__(256) void k_scatter(const int* __restrict__ ei,
                                                 int* __restrict__ cursor,
                                                 int* __restrict__ csr_src)
{
    int e = blockIdx.x * blockDim.x + threadIdx.x;
    if (e >= ETOT) return;
    int src, dst;
    if (e < EE) { src = ei[e]; dst = ei[EE + e]; }
    else        { src = dst = e - EE; }
    int pos = atomicAdd(&cursor[dst], 1);
    csr_src[pos] = src;
}

// ---------------- MFMA GEMM: both operands LDS-staged, fused alpha epilogue --------------
// 512 threads = 8 waves (4 M-groups x 2 N-groups), block = 64 rows x 128 cols.
// Head hh = wn*4+t owns exactly the 16 cols of accumulator tile t -> attention logits
// as/ad are a 16-lane shfl reduce of the fp32 accumulator.
template<int KDIM, bool A_BF16>
__global__ __launch_bounds__(512, 4) void k_gemm2(const void* __restrict__ Ap,
                                                  const short* __restrict__ Wt,
                                                  short* __restrict__ C,
                                                  int M,
                                                  const float* __restrict__ a_s,
                                                  const float* __restrict__ a_d,
                                                  float* __restrict__ as_o,
                                                  float* __restrict__ ad_o)
{
    constexpr int KCH  = 128;              // k-chunk
    constexpr int NCH  = KDIM / KCH;       // chunks (layer0: 4, layer1: 1)
    constexpr int LROW = KCH + 8;          // shorts per LDS row (+pad: banks)
    __shared__ short As[64 * LROW];        // 17.4 KB
    __shared__ short Bs[128 * LROW];       // 34.8 KB  -> 52.2 KB total, 3 blocks/CU

    const int tid  = threadIdx.x;
    const int wv   = tid >> 6;
    const int lane = tid & 63;
    const int quad = lane >> 4;
    const int col  = lane & 15;
    const int wr   = wv >> 1;              // M-group 0..3  (16 rows each)
    const int wn   = wv & 1;               // N-group 0..1  (64 cols each)
    const int rowbase = blockIdx.x * 64;

    const float* Af = (const float*)Ap;
    const short* Ab = (const short*)Ap;

    float4 pa[4];                          // fp32 A staging regs (layer 0)
    bf16x8 pab[2];                         // bf16 A staging regs (layer 1)
    bf16x8 pb[4];                          // B staging regs

    auto loadA = [&](int c) {
        if constexpr (A_BF16) {
            #pragma unroll
            for (int r = 0; r < 2; ++r) {
                int gr = rowbase + r * 32 + (tid >> 4);
                gr = gr < M ? gr : M - 1;
                pab[r] = *(const bf16x8*)(Ab + (size_t)gr * KDIM + c * KCH + (tid & 15) * 8);
            }
        } else {
            #pragma unroll
            for (int r = 0; r < 4; ++r) {
                int gr = rowbase + r * 16 + (tid >> 5);
                gr = gr < M ? gr : M - 1;
                pa[r] = *(const float4*)(Af + (size_t)gr * KDIM + c * KCH + (tid & 31) * 4);
            }
        }
    };
    auto loadB = [&](int c) {
        #pragma unroll
        for (int r = 0; r < 4; ++r) {
            int n = r * 32 + (tid >> 4);
            pb[r] = *(const bf16x8*)(Wt + (size_t)n * KDIM + c * KCH + (tid & 15) * 8);
        }
    };
    auto writeAB = [&]() {
        if constexpr (A_BF16) {
            #pragma unroll
            for (int r = 0; r < 2; ++r) {
                int row = r * 32 + (tid >> 4);
                *(bf16x8*)(As + row * LROW + (tid & 15) * 8) = pab[r];
            }
        } else {
            #pragma unroll
            for (int r = 0; r < 4; ++r) {
                int row = r * 16 + (tid >> 5);
                bf16x4 w;
                w[0] = f2b(pa[r].x); w[1] = f2b(pa[r].y);
                w[2] = f2b(pa[r].z); w[3] = f2b(pa[r].w);
                *(bf16x4*)(As + row * LROW + (tid & 31) * 4) = w;
            }
        }
        #pragma unroll
        for (int r = 0; r < 4; ++r) {
            int n = r * 32 + (tid >> 4);
            *(bf16x8*)(Bs + n * LROW + (tid & 15) * 8) = pb[r];
        }
    };

    f32x4 acc[4];
    #pragma unroll
    for (int t = 0; t < 4; ++t) acc[t] = (f32x4){0.f, 0.f, 0.f, 0.f};

    loadA(0); loadB(0);

    for (int c = 0; c < NCH; ++c) {
        writeAB();
        __syncthreads();
        if (c + 1 < NCH) { loadA(c + 1); loadB(c + 1); }   // fly under MFMA phase
        #pragma unroll
        for (int s = 0; s < KCH / 32; ++s) {
            bf16x8 af = *(const bf16x8*)(As + (wr * 16 + col) * LROW + s * 32 + quad * 8);
            #pragma unroll
            for (int t = 0; t < 4; ++t) {
                bf16x8 bf = *(const bf16x8*)(Bs + (wn * 64 + t * 16 + col) * LROW + s * 32 + quad * 8);
                acc[t] = __builtin_amdgcn_mfma_f32_16x16x32_bf16(af, bf, acc[t], 0, 0, 0);
            }
        }
        if (c + 1 < NCH) __syncthreads();
    }

    const int mb = rowbase + wr * 16 + quad * 4;

    // C write (bf16)
    #pragma unroll
    for (int t = 0; t < 4; ++t) {
        int cc = wn * 64 + t * 16 + col;
        #pragma unroll
        for (int r = 0; r < 4; ++r) {
            int m = mb + r;
            if (m < M) C[(size_t)m * HCH + cc] = f2b(acc[t][r]);
        }
    }

    // fused attention logits: head hh = wn*4+t; 16-lane reduce over col
    #pragma unroll
    for (int t = 0; t < 4; ++t) {
        int hh = wn * 4 + t;
        float ws = a_s[hh * HIDC + col];
        float wd = a_d[hh * HIDC + col];
        #pragma unroll
        for (int r = 0; r < 4; ++r) {
            float vs = acc[t][r] * ws;
            float vd = acc[t][r] * wd;
            vs += __shfl_xor(vs, 1);  vd += __shfl_xor(vd, 1);
            vs += __shfl_xor(vs, 2);  vd += __shfl_xor(vd, 2);
            vs += __shfl_xor(vs, 4);  vd += __shfl_xor(vd, 4);
            vs += __shfl_xor(vs, 8);  vd += __shfl_xor(vd, 8);
            int m = mb + r;
            if (col == 0 && m < M) {
                as_o[m * NH + hh] = vs;
                ad_o[m * NH + hh] = vd;
            }
        }
    }
}

// ---------------- layer-2 GEMM (N=48 padded tile) with fused alpha2 epilogue --------------
template<int KDIM, int NTILES, bool A_BF16>
__global__ __launch_bounds__(256) void k_gemm_lds(const void* __restrict__ Ap,
                                                  const short* __restrict__ Wt,
                                                  short* __restrict__ C,
                                                  int M, int N,
                                                  const float* __restrict__ a_s2,
                                                  const float* __restrict__ a_d2,
                                                  float* __restrict__ as_o,
                                                  float* __restrict__ ad_o)
{
    constexpr int NFULL = NTILES * 16;
    constexpr int KCH = 128;               // k-chunk
    constexpr int NK = KDIM / 32;          // total ksteps
    constexpr int NCH = KDIM / KCH;        // chunks
    constexpr int LROW = KCH + 8;          // shorts per LDS row
    __shared__ short Bs[NFULL * LROW];

    const int tid  = threadIdx.x;
    const int wave = tid >> 6;
    const int lane = tid & 63;
    const int quad = lane >> 4;
    const int col  = lane & 15;
    const int row  = blockIdx.x * 64 + wave * 16 + col;
    const int arow = row < M ? row : M - 1;

    f32x4 acc[NTILES];
    #pragma unroll
    for (int t = 0; t < NTILES; ++t) acc[t] = (f32x4){0.f, 0.f, 0.f, 0.f};

    bf16x8 arB[4];
    float4 arF[4][2];
    const short* Ab = (const short*)Ap;
    const float* Af = (const float*)Ap;
    auto pf = [&](int ks) {
        if (ks >= NK) return;
        if (A_BF16) {
            arB[ks & 3] = *(const bf16x8*)(Ab + (size_t)arow * KDIM + ks * 32 + quad * 8);
        } else {
            const float4* p = (const float4*)(Af + (size_t)arow * KDIM + ks * 32 + quad * 8);
            arF[ks & 3][0] = p[0];
            arF[ks & 3][1] = p[1];
        }
    };
    pf(0); pf(1); pf(2); pf(3);

    for (int c = 0; c < NCH; ++c) {
        const int k0 = c * KCH;
        constexpr int TOT8 = NFULL * (KCH / 8);
        #pragma unroll
        for (int i = tid; i < TOT8; i += 256) {
            int n  = i >> 4;
            int kk = i & 15;
            bf16x8 v = *(const bf16x8*)(Wt + (size_t)n * KDIM + k0 + kk * 8);
            *(bf16x8*)(Bs + n * LROW + kk * 8) = v;
        }
        __syncthreads();
        #pragma unroll
        for (int s = 0; s < KCH / 32; ++s) {
            const int ks = c * (KCH / 32) + s;
            bf16x8 afrag;
            if (A_BF16) {
                afrag = arB[ks & 3];
            } else {
                float4 v0 = arF[ks & 3][0], v1 = arF[ks & 3][1];
                afrag[0] = f2b(v0.x); afrag[1] = f2b(v0.y);
                afrag[2] = f2b(v0.z); afrag[3] = f2b(v0.w);
                afrag[4] = f2b(v1.x); afrag[5] = f2b(v1.y);
                afrag[6] = f2b(v1.z); afrag[7] = f2b(v1.w);
            }
            pf(ks + 4);
            #pragma unroll
            for (int t = 0; t < NTILES; ++t) {
                bf16x8 bfrag = *(const bf16x8*)(Bs + (t * 16 + col) * LROW + s * 32 + quad * 8);
                acc[t] = __builtin_amdgcn_mfma_f32_16x16x32_bf16(afrag, bfrag, acc[t], 0, 0, 0);
            }
        }
        if (c + 1 < NCH) __syncthreads();
    }

    const int mbase = blockIdx.x * 64 + wave * 16 + quad * 4;
    #pragma unroll
    for (int t = 0; t < NTILES; ++t) {
        int cc = t * 16 + col;
        if (cc < N) {
            #pragma unroll
            for (int r = 0; r < 4; ++r) {
                int m = mbase + r;
                if (m < M) C[(size_t)m * N + cc] = f2b(acc[t][r]);
            }
        }
    }

    // fused alpha2: single head spanning cols 0..39 (cols >= 40 have zero W -> acc==0)
    float vs[4] = {0.f, 0.f, 0.f, 0.f};
    float vd[4] = {0.f, 0.f, 0.f, 0.f};
    #pragma unroll
    for (int t = 0; t < NTILES; ++t) {
        int cc = t * 16 + col;
        float ws = cc < NLBL ? a_s2[cc] : 0.f;
        float wd = cc < NLBL ? a_d2[cc] : 0.f;
        #pragma unroll
        for (int r = 0; r < 4; ++r) {
            vs[r] += acc[t][r] * ws;
            vd[r] += acc[t][r] * wd;
        }
    }
    #pragma unroll
    for (int r = 0; r < 4; ++r) {
        float s = vs[r], d = vd[r];
        s += __shfl_xor(s, 1);  d += __shfl_xor(d, 1);
        s += __shfl_xor(s, 2);  d += __shfl_xor(d, 2);
        s += __shfl_xor(s, 4);  d += __shfl_xor(d, 4);
        s += __shfl_xor(s, 8);  d += __shfl_xor(d, 8);
        int m = mbase + r;
        if (col == 0 && m < M) {
            as_o[m] = s;
            ad_o[m] = d;
        }
    }
}

// ---------------- pull aggregation: half-wave per edge stream, 4-deep unroll ----------------
__global__ __launch_bounds__(256) void k_agg(const int* __restrict__ row_ptr,
                                             const int* __restrict__ csr_src,
                                             const unsigned short* __restrict__ h,
                                             const float* __restrict__ as,
                                             const float* __restrict__ ad,
                                             const float* __restrict__ b,
                                             const float* __restrict__ g,
                                             const float* __restrict__ be,
                                             const float* __restrict__ rm,
                                             const float* __restrict__ rv,
                                             short* __restrict__ out)
{
    int n = blockIdx.x * 4 + (threadIdx.x >> 6);
    if (n >= NN) return;
    int lane = threadIdx.x & 63;
    int half = lane >> 5;
    int c4 = lane & 31;                  // channel group: channels 4*c4 .. 4*c4+3
    int hh = c4 >> 2;                    // head
    float adv = ad[n * NH + hh];
    float a0 = 0.f, a1 = 0.f, a2 = 0.f, a3 = 0.f, sw = 0.f;
    int jb = row_ptr[n], je = row_ptr[n + 1];
    int j = jb + half;
    for (; j + 6 < je; j += 8) {
        int s0 = csr_src[j];
        int s1 = csr_src[j + 2];
        int s2 = csr_src[j + 4];
        int s3 = csr_src[j + 6];
        float l0 = as[s0 * NH + hh] + adv;
        float l1 = as[s1 * NH + hh] + adv;
        float l2 = as[s2 * NH + hh] + adv;
        float l3 = as[s3 * NH + hh] + adv;
        uint2 u0 = *(const uint2*)(h + (size_t)s0 * HCH + 4 * c4);
        uint2 u1 = *(const uint2*)(h + (size_t)s1 * HCH + 4 * c4);
        uint2 u2 = *(const uint2*)(h + (size_t)s2 * HCH + 4 * c4);
        uint2 u3 = *(const uint2*)(h + (size_t)s3 * HCH + 4 * c4);
        l0 = l0 > 0.f ? l0 : NEG_SLOPE * l0;
        l1 = l1 > 0.f ? l1 : NEG_SLOPE * l1;
        l2 = l2 > 0.f ? l2 : NEG_SLOPE * l2;
        l3 = l3 > 0.f ? l3 : NEG_SLOPE * l3;
        float w0 = __expf(l0), w1 = __expf(l1), w2 = __expf(l2), w3 = __expf(l3);
        sw += (w0 + w1) + (w2 + w3);
        a0 += w0 * blo(u0.x) + w1 * blo(u1.x) + w2 * blo(u2.x) + w3 * blo(u3.x);
        a1 += w0 * bhi(u0.x) + w1 * bhi(u1.x) + w2 * bhi(u2.x) + w3 * bhi(u3.x);
        a2 += w0 * blo(u0.y) + w1 * blo(u1.y) + w2 * blo(u2.y) + w3 * blo(u3.y);
        a3 += w0 * bhi(u0.y) + w1 * bhi(u1.y) + w2 * bhi(u2.y) + w3 * bhi(u3.y);
    }
    for (; j < je; j += 2) {
        int s0 = csr_src[j];
        float l0 = as[s0 * NH + hh] + adv;
        uint2 u0 = *(const uint2*)(h + (size_t)s0 * HCH + 4 * c4);
        l0 = l0 > 0.f ? l0 : NEG_SLOPE * l0;
        float w0 = __expf(l0);
        sw += w0;
        a0 += w0 * blo(u0.x);
        a1 += w0 * bhi(u0.x);
        a2 += w0 * blo(u0.y);
        a3 += w0 * bhi(u0.y);
    }
    // combine the two half-waves
    a0 += __shfl_down(a0, 32);
    a1 += __shfl_down(a1, 32);
    a2 += __shfl_down(a2, 32);
    a3 += __shfl_down(a3, 32);
    sw += __shfl_down(sw, 32);
    if (half == 0) {
        int c = 4 * c4;
        float inv = 1.f / (sw + 1e-16f);
        float4 bv  = *(const float4*)(b + c);
        float4 gv  = *(const float4*)(g + c);
        float4 bev = *(const float4*)(be + c);
        float4 rmv = *(const float4*)(rm + c);
        float4 rvv = *(const float4*)(rv + c);
        float r0 = a0 * inv + bv.x;
        float r1 = a1 * inv + bv.y;
        float r2 = a2 * inv + bv.z;
        float r3 = a3 * inv + bv.w;
        r0 = (r0 - rmv.x) * (gv.x * rsqrtf(rvv.x + BN_EPS)) + bev.x;
        r1 = (r1 - rmv.y) * (gv.y * rsqrtf(rvv.y + BN_EPS)) + bev.y;
        r2 = (r2 - rmv.z) * (gv.z * rsqrtf(rvv.z + BN_EPS)) + bev.z;
        r3 = (r3 - rmv.w) * (gv.w * rsqrtf(rvv.w + BN_EPS)) + bev.w;
        r0 = r0 > 0.f ? r0 : ELU_A * expm1f(r0);
        r1 = r1 > 0.f ? r1 : ELU_A * expm1f(r1);
        r2 = r2 > 0.f ? r2 : ELU_A * expm1f(r2);
        r3 = r3 > 0.f ? r3 : ELU_A * expm1f(r3);
        unsigned int lo = (unsigned int)(unsigned short)f2b(r0) |
                          ((unsigned int)(unsigned short)f2b(r1) << 16);
        unsigned int hi = (unsigned int)(unsigned short)f2b(r2) |
                          ((unsigned int)(unsigned short)f2b(r3) << 16);
        *(uint2*)(out + (size_t)n * HCH + c) = make_uint2(lo, hi);
    }
}

// layer-2: 1 head, 40 ch bf16 gather, half-wave per edge stream, 4-deep unroll, fp32 out
__global__ __launch_bounds__(256) void k_agg2(const int* __restrict__ row_ptr,
                                              const int* __restrict__ csr_src,
                                              const unsigned short* __restrict__ h2,
                                              const float* __restrict__ as,
                                              const float* __restrict__ ad,
                                              const float* __restrict__ b,
                                              float* __restrict__ out)
{
    int n = blockIdx.x * 4 + (threadIdx.x >> 6);
    if (n >= NN) return;
    int lane = threadIdx.x & 63;
    int half = lane >> 5;                // which edge stream
    int c2 = lane & 31;                  // channel-pair index; active if c2 < 20
    bool act = c2 < 20;
    int coff = act ? 2 * c2 : 0;
    float adv = ad[n];
    float acc0 = 0.f, acc1 = 0.f, sw = 0.f;
    int jb = row_ptr[n], je = row_ptr[n + 1];
    int j = jb + half;
    for (; j + 6 < je; j += 8) {
        int s0 = csr_src[j];
        int s1 = csr_src[j + 2];
        int s2 = csr_src[j + 4];
        int s3 = csr_src[j + 6];
        float l0 = as[s0] + adv;
        float l1 = as[s1] + adv;
        float l2 = as[s2] + adv;
        float l3 = as[s3] + adv;
        unsigned int u0 = *(const unsigned int*)(h2 + (size_t)s0 * NLBL + coff);
        unsigned int u1 = *(const unsigned int*)(h2 + (size_t)s1 * NLBL + coff);
        unsigned int u2 = *(const unsigned int*)(h2 + (size_t)s2 * NLBL + coff);
        unsigned int u3 = *(const unsigned int*)(h2 + (size_t)s3 * NLBL + coff);
        l0 = l0 > 0.f ? l0 : NEG_SLOPE * l0;
        l1 = l1 > 0.f ? l1 : NEG_SLOPE * l1;
        l2 = l2 > 0.f ? l2 : NEG_SLOPE * l2;
        l3 = l3 > 0.f ? l3 : NEG_SLOPE * l3;
        float w0 = __expf(l0), w1 = __expf(l1), w2 = __expf(l2), w3 = __expf(l3);
        sw += (w0 + w1) + (w2 + w3);
        if (act) {
            acc0 += w0 * blo(u0) + w1 * blo(u1) + w2 * blo(u2) + w3 * blo(u3);
            acc1 += w0 * bhi(u0) + w1 * bhi(u1) + w2 * bhi(u2) + w3 * bhi(u3);
        }
    }
    for (; j < je; j += 2) {
        int s = csr_src[j];
        float l = as[s] + adv;
        unsigned int u = *(const unsigned int*)(h2 + (size_t)s * NLBL + coff);
        l = l > 0.f ? l : NEG_SLOPE * l;
        float w = __expf(l);
        sw += w;
        if (act) {
            acc0 += w * blo(u);
            acc1 += w * bhi(u);
        }
    }
    float acc0b = __shfl_down(acc0, 32);
    float acc1b = __shfl_down(acc1, 32);
    float swb   = __shfl_down(sw, 32);
    if (half == 0 && act) {
        acc0 += acc0b; acc1 += acc1b; sw += swb;
        float inv = 1.f / (sw + 1e-16f);
        out[(size_t)n * NLBL + 2 * c2]     = acc0 * inv + b[2 * c2];
        out[(size_t)n * NLBL + 2 * c2 + 1] = acc1 * inv + b[2 * c2 + 1];
    }
}

extern "C" void kernel_launch(void* const* d_in, const int* in_sizes, int n_in,
                              void* d_out, int out_size, void* d_ws, size_t ws_size,
                              hipStream_t stream)
{
    const float* x   = (const float*)d_in[0];
    const int*   ei  = (const int*)d_in[1];
    const float* W0  = (const float*)d_in[2];
    const float* as0 = (const float*)d_in[3];
    const float* ad0 = (const float*)d_in[4];
    const float* b0  = (const float*)d_in[5];
    const float* g0  = (const float*)d_in[6];
    const float* be0 = (const float*)d_in[7];
    const float* rm0 = (const float*)d_in[8];
    const float* rv0 = (const float*)d_in[9];
    const float* W1  = (const float*)d_in[10];
    const float* as1 = (const float*)d_in[11];
    const float* ad1 = (const float*)d_in[12];
    const float* b1  = (const float*)d_in[13];
    const float* g1  = (const float*)d_in[14];
    const float* be1 = (const float*)d_in[15];
    const float* rm1 = (const float*)d_in[16];
    const float* rv1 = (const float*)d_in[17];
    const float* W2  = (const float*)d_in[18];
    const float* a_s2 = (const float*)d_in[19];
    const float* a_d2 = (const float*)d_in[20];
    const float* b2  = (const float*)d_in[21];
    float* out = (float*)d_out;

    char* ws = (char*)d_ws;
    size_t off = 0;
    auto alloc = [&](size_t bytes) {
        void* p = (void*)(ws + off);
        off += (bytes + 255) & ~(size_t)255;
        return p;
    };
    short* hbuf   = (short*)alloc((size_t)NN * HCH * 2);   // bf16 GEMM out / gather source
    short* fbuf   = (short*)alloc((size_t)NN * HCH * 2);   // bf16 aggregated features (GEMM A input)
    float* asb    = (float*)alloc((size_t)NN * NH * 4);
    float* adb    = (float*)alloc((size_t)NN * NH * 4);
    int*   deg    = (int*)alloc((size_t)NN * 4);
    int*   rowp   = (int*)alloc((size_t)(NN + 1) * 4);
    int*   cursor = (int*)alloc((size_t)NN * 4);
    int*   csrs   = (int*)alloc((size_t)ETOT * 4);
    short* Wt0    = (short*)alloc((size_t)HCH * FIN * 2);
    short* Wt1    = (short*)alloc((size_t)HCH * HCH * 2);
    short* Wt2    = (short*)alloc((size_t)NLBLP * HCH * 2);
    int*   tot    = (int*)alloc(64 * 4);
    int*   totp   = (int*)alloc(64 * 4);
    short* h2     = hbuf;   // reuse: hbuf dead by layer 2

    const int T = 256;
    const int gN4 = (NN + 3) / 4;
    const int gM  = (NN + 63) / 64;        // 782
    const int gPrep = 256 + 64 + 24 + (ETOT + T - 1) / T;   // 3665
    const int gE  = (ETOT + T - 1) / T;

    // ---------- prep: weight transpose/convert + degree histogram (one launch) ----------
    hipMemsetAsync(deg, 0, (size_t)NN * 4, stream);
    k_prep<<<gPrep, T, 0, stream>>>(W0, Wt0, W1, Wt1, W2, Wt2, ei, deg);

    // ---------- multi-block scan + scatter ----------
    k_scan1<<<NCHK, 1024, 0, stream>>>(deg, rowp, tot);
    k_scan2<<<1, 64, 0, stream>>>(tot, totp, rowp);
    k_scan3<<<(NN + T - 1) / T, T, 0, stream>>>(rowp, cursor, totp);
    k_scatter<<<gE, T, 0, stream>>>(ei, cursor, csrs);

    // ---------- layer 0 (GEMM + fused alpha epilogue) ----------
    k_gemm2<FIN, false><<<gM, 512, 0, stream>>>(x, Wt0, hbuf, NN, as0, ad0, asb, adb);
    k_agg<<<gN4, T, 0, stream>>>(rowp, csrs, (const unsigned short*)hbuf, asb, adb,
                                 b0, g0, be0, rm0, rv0, fbuf);

    // ---------- layer 1 ----------
    k_gemm2<HCH, true><<<gM, 512, 0, stream>>>(fbuf, Wt1, hbuf, NN, as1, ad1, asb, adb);
    k_agg<<<gN4, T, 0, stream>>>(rowp, csrs, (const unsigned short*)hbuf, asb, adb,
                                 b1, g1, be1, rm1, rv1, fbuf);

    // ---------- layer 2 (GEMM + fused alpha2 epilogue) ----------
    k_gemm_lds<HCH, 3, true><<<gM, T, 0, stream>>>(fbuf, Wt2, h2, NN, NLBL,
                                                   a_s2, a_d2, asb, adb);
    k_agg2<<<gN4, T, 0, stream>>>(rowp, csrs, (const unsigned short*)h2, asb, adb, b2, out);
}